// Round 14
// baseline (353.768 us; speedup 1.0000x reference)
//
#include <hip/hip_runtime.h>
#include <hip/hip_bf16.h>

typedef __attribute__((ext_vector_type(8))) short short8;   // bf16x8 (4 VGPR)
typedef __attribute__((ext_vector_type(4))) float f32x4;
typedef __attribute__((ext_vector_type(2))) float f32x2;
typedef __attribute__((ext_vector_type(4))) int i32x4;
typedef __attribute__((ext_vector_type(2))) int i32x2;

typedef unsigned short u16;
typedef unsigned int u32;

#define DEVI static __device__ __forceinline__

constexpr int Bn = 8, Nn = 1024, Dn = 768, Hn = 12;
constexpr int Rn = Bn * Nn;                 // 8192 rows
constexpr int LDQ = 3 * Dn;                 // merged QKV row stride (2304)
constexpr int KOFF = Dn, VOFF = 2 * Dn;     // K/V column offsets in QKV
constexpr float SCALE = 0.125f;             // (768/12)^-0.5 = 1/8
constexpr float LOG2E = 1.44269504088896340736f;
constexpr int HPB = 4;                      // heads per qk block (12 = 3 groups)

// S scratch layout: [bb][n][h][m]  (h-interleaved: one (b,n) row's 12 heads
// are a contiguous 24KB slab -> mid_kernel streams, L2/L3 friendly)
DEVI size_t sidx(int bb, int n, int h) {
    return (((size_t)bb * Nn + n) * Hn + h) * Nn;
}

DEVI u16 f2bf(float f) {
    __hip_bfloat16 h = __float2bfloat16(f);
    return __builtin_bit_cast(u16, h);
}

// RNE bf16 pack of two floats (bit-identical to __float2bfloat16 for finite x)
DEVI u32 bfpack(float a, float b) {
    u32 xa = __builtin_bit_cast(u32, a);
    u32 xb = __builtin_bit_cast(u32, b);
    xa += 0x7fffu + ((xa >> 16) & 1u);
    xb += 0x7fffu + ((xb >> 16) & 1u);
    return (xa >> 16) | (xb & 0xffff0000u);
}

#if __has_builtin(__builtin_amdgcn_exp2f)
#define EXP2(x) __builtin_amdgcn_exp2f(x)
#else
#define EXP2(x) exp2f(x)
#endif
#if __has_builtin(__builtin_amdgcn_rcpf)
#define RCP(x) __builtin_amdgcn_rcpf(x)
#else
#define RCP(x) (1.0f / (x))
#endif

// async global->LDS, 16B per lane; LDS dest must be wave-uniform base + lane*16
DEVI void gload16(const u16* g, u16* l) {
    __builtin_amdgcn_global_load_lds(
        (const __attribute__((address_space(1))) void*)g,
        (__attribute__((address_space(3))) void*)l,
        16, 0, 0);
}

// ---------------- f32 -> bf16 convert, 4 elems/thread ----------------
__global__ __launch_bounds__(256) void cvt4_kernel(const float* __restrict__ in,
                                                   u16* __restrict__ out, int n4) {
    int i = blockIdx.x * 256 + threadIdx.x;
    if (i >= n4) return;
    f32x4 v = *reinterpret_cast<const f32x4*>(&in[(size_t)i * 4]);
    u16 o[4];
#pragma unroll
    for (int j = 0; j < 4; ++j) o[j] = f2bf(v[j]);
    *reinterpret_cast<u32*>(&out[(size_t)i * 4]) = (u32)o[0] | ((u32)o[1] << 16);
    *reinterpret_cast<u32*>(&out[(size_t)i * 4 + 2]) = (u32)o[2] | ((u32)o[3] << 16);
}

// 4 weight matrices (same size) in one launch; blockIdx.y selects the matrix
__global__ __launch_bounds__(256) void cvtw_kernel(const float* __restrict__ a,
                                                   const float* __restrict__ b,
                                                   const float* __restrict__ c,
                                                   const float* __restrict__ d,
                                                   u16* oa, u16* ob, u16* oc, u16* od,
                                                   int n4) {
    int i = blockIdx.x * 256 + threadIdx.x;
    if (i >= n4) return;
    const float* in; u16* out;
    switch (blockIdx.y) {
        case 0: in = a; out = oa; break;
        case 1: in = b; out = ob; break;
        case 2: in = c; out = oc; break;
        default: in = d; out = od; break;
    }
    f32x4 v = *reinterpret_cast<const f32x4*>(&in[(size_t)i * 4]);
    u16 o[4];
#pragma unroll
    for (int j = 0; j < 4; ++j) o[j] = f2bf(v[j]);
    *reinterpret_cast<u32*>(&out[(size_t)i * 4]) = (u32)o[0] | ((u32)o[1] << 16);
    *reinterpret_cast<u32*>(&out[(size_t)i * 4 + 2]) = (u32)o[2] | ((u32)o[3] << 16);
}

// concat 3 bias vectors of Dn floats -> one 3*Dn array
__global__ __launch_bounds__(256) void bcat_kernel(const float* __restrict__ a,
                                                   const float* __restrict__ b,
                                                   const float* __restrict__ c,
                                                   float* __restrict__ o) {
    int i = blockIdx.x * 256 + threadIdx.x;
    if (i < Dn) o[i] = a[i];
    else if (i < 2 * Dn) o[i] = b[i - Dn];
    else if (i < 3 * Dn) o[i] = c[i - 2 * Dn];
}

// ---------------- 128x128 NT GEMM: C[M,Nc] = A[M,K]*B[Nc,K]^T + bias ----------------
// 2-phase double-buffered pipeline, seg-swizzled LDS, XCD block swizzle.
template <bool BF16OUT>
__global__ __launch_bounds__(256) void gemm128(const u16* __restrict__ A,
                                               const u16* __restrict__ Bm,
                                               const float* __restrict__ bias,
                                               void* __restrict__ Cv,
                                               int M, int Nc, int K) {
    __shared__ u16 lA[2][128 * 32];
    __shared__ u16 lB[2][128 * 32];
    int tid = threadIdx.x, wave = tid >> 6, lane = tid & 63;
    int wr = (wave >> 1) * 64, wc = (wave & 1) * 64;

    int nwg = gridDim.x * gridDim.y;
    int bid = blockIdx.y * gridDim.x + blockIdx.x;
    if ((nwg & 7) == 0) {
        int cpx = nwg >> 3;
        bid = (bid & 7) * cpx + (bid >> 3);
    }
    int row0 = (bid / gridDim.x) * 128, col0 = (bid % gridDim.x) * 128;

    f32x4 acc[4][4] = {};

    int sseg = (tid & 3) ^ ((tid >> 3) & 3);
    const u16* gA = A + (size_t)(row0 + (tid >> 2)) * K + sseg * 8;
    const u16* gB = Bm + (size_t)(col0 + (tid >> 2)) * K + sseg * 8;

    auto stage = [&](int buf, int k0) {
        gload16(gA + k0, &lA[buf][tid * 8]);
        gload16(gA + k0 + (size_t)64 * K, &lA[buf][tid * 8 + 2048]);
        gload16(gB + k0, &lB[buf][tid * 8]);
        gload16(gB + k0 + (size_t)64 * K, &lB[buf][tid * 8 + 2048]);
    };

    int sw8 = (((lane >> 4) ^ ((lane >> 1) & 3))) * 8;

    int nt = K / 32;
    stage(0, 0);
    __syncthreads();

    int cur = 0;
    for (int t = 0; t < nt; ++t) {
        if (t + 1 < nt) stage(cur ^ 1, (t + 1) * 32);

        short8 af[4], bf[4];
#pragma unroll
        for (int a = 0; a < 4; ++a)
            af[a] = *reinterpret_cast<const short8*>(
                &lA[cur][(wr + a * 16 + (lane & 15)) * 32 + sw8]);
#pragma unroll
        for (int c = 0; c < 4; ++c)
            bf[c] = *reinterpret_cast<const short8*>(
                &lB[cur][(wc + c * 16 + (lane & 15)) * 32 + sw8]);
#pragma unroll
        for (int a = 0; a < 4; ++a)
#pragma unroll
            for (int c = 0; c < 4; ++c)
                acc[a][c] = __builtin_amdgcn_mfma_f32_16x16x32_bf16(af[a], bf[c], acc[a][c], 0, 0, 0);

        __syncthreads();
        cur ^= 1;
    }

#pragma unroll
    for (int a = 0; a < 4; ++a) {
        int crow = row0 + wr + a * 16 + (lane >> 4) * 4;
#pragma unroll
        for (int c = 0; c < 4; ++c) {
            int col = col0 + wc + c * 16 + (lane & 15);
            float bv = bias ? bias[col] : 0.f;
#pragma unroll
            for (int r = 0; r < 4; ++r) {
                float v = acc[a][c][r] + bv;
                if (BF16OUT)
                    reinterpret_cast<u16*>(Cv)[(size_t)(crow + r) * Nc + col] = f2bf(v);
                else
                    reinterpret_cast<float*>(Cv)[(size_t)(crow + r) * Nc + col] = v;
            }
        }
    }
}

// ---------------- batched QK^T, HPB=4 heads per block ----------------
// Stage Q[64n x 256] and K[64m x 256] (4 contiguous head-bands) once -> 64KB LDS,
// compute 4 head-tiles (128 MFMA/block). Row = 256 elems (512B); seg-swizzle
// seg^=(row&7) via pre-swizzled gload source + swizzled read (2-way, free).
__global__ __launch_bounds__(256) void qk_kernel(const u16* __restrict__ QKV,
                                                 u16* __restrict__ S, int b0) {
    __shared__ u16 lQ[64 * 64 * HPB];
    __shared__ u16 lK[64 * 64 * HPB];
    int z = blockIdx.z, hg = z % (Hn / HPB), bb = z / (Hn / HPB), b = b0 + bb;
    int h0 = hg * HPB;
    int n0 = blockIdx.y * 64, m0 = blockIdx.x * 64;
    int tid = threadIdx.x, wave = tid >> 6, lane = tid & 63;

    // stage: chunk c = i*256 + tid; row = c>>5, seg = c&31; source col pre-swizzled
    {
        int seg = tid & 31;
#pragma unroll
        for (int i = 0; i < 8; ++i) {
            int row = i * 8 + (tid >> 5);
            int scol = (seg ^ (row & 7)) * 8;
            const u16* gQ = QKV + ((size_t)(b * Nn) + n0 + row) * LDQ + h0 * 64 + scol;
            const u16* gK = QKV + ((size_t)(b * Nn) + m0 + row) * LDQ + KOFF + h0 * 64 + scol;
            gload16(gQ, &lQ[i * 2048 + tid * 8]);
            gload16(gK, &lK[i * 2048 + tid * 8]);
        }
    }
    __syncthreads();

    f32x4 acc[HPB][4] = {};
#pragma unroll
    for (int hh = 0; hh < HPB; ++hh) {
#pragma unroll
        for (int kk = 0; kk < 2; ++kk) {
            int segd = hh * 8 + kk * 4 + (lane >> 4);      // desired 16B seg in row
            int rK = wave * 16 + (lane & 15);
            short8 bf = *reinterpret_cast<const short8*>(
                &lK[rK * 256 + ((segd ^ (rK & 7)) * 8)]);
#pragma unroll
            for (int a = 0; a < 4; ++a) {
                int rQ = a * 16 + (lane & 15);
                short8 af = *reinterpret_cast<const short8*>(
                    &lQ[rQ * 256 + ((segd ^ (rQ & 7)) * 8)]);
                acc[hh][a] = __builtin_amdgcn_mfma_f32_16x16x32_bf16(af, bf, acc[hh][a], 0, 0, 0);
            }
        }
    }

    int col = m0 + wave * 16 + (lane & 15);
#pragma unroll
    for (int hh = 0; hh < HPB; ++hh)
#pragma unroll
        for (int a = 0; a < 4; ++a) {
            int rowb = n0 + a * 16 + (lane >> 4) * 4;
#pragma unroll
            for (int r = 0; r < 4; ++r)
                S[sidx(bb, rowb + r, h0 + hh) + col] = f2bf(acc[hh][a][r] * SCALE);
        }
}

// ---------------- fused mix1 + softmax + mix2 (in place on S) ----------------
// R8 form (proven best): one block (256 thr) per (bb, n) row; 4 m-positions per
// thread. f32x2 vector math, raw v_exp_f32, v_rcp_f32, manual RNE pack.
// No max-subtraction: |logits| bounded, f32 exp cannot overflow.
__global__ __launch_bounds__(256) void mid_kernel(u16* __restrict__ S,
                                                  const float* __restrict__ w1p,
                                                  const float* __restrict__ b1p,
                                                  const float* __restrict__ w2p,
                                                  const float* __restrict__ b2p) {
    __shared__ float w1[Hn * Hn], w2[Hn * Hn], b1v[Hn], b2v[Hn];
    __shared__ float redS[4][Hn];
    int tid = threadIdx.x;
    for (int i = tid; i < Hn * Hn; i += 256) {
        int g = i % Hn, h = i / Hn;           // store transposed: w[h][g]
        w1[i] = w1p[g * Hn + h] * LOG2E;      // exp2-direct prescale
        w2[i] = w2p[g * Hn + h];
    }
    if (tid < Hn) { b1v[tid] = b1p[tid] * LOG2E; b2v[tid] = b2p[tid]; }
    __syncthreads();

    int bb = blockIdx.x >> 10, n = blockIdx.x & 1023;
    size_t base0 = sidx(bb, n, 0) + tid * 4;      // + h*Nn per head plane

    // prefetch ALL 12 head slabs (12 outstanding dwordx2 loads, one wait)
    i32x2 sv[Hn];
#pragma unroll
    for (int h = 0; h < Hn; ++h)
        sv[h] = *reinterpret_cast<const i32x2*>(&S[base0 + h * Nn]);

    // mix1 (f32x2): acc[g] = b1s[g] + sum_h w1s[g,h] * S[h]   (log2-scaled)
    f32x2 acc[Hn][2];
#pragma unroll
    for (int g = 0; g < Hn; ++g) {
        float b = b1v[g];
        acc[g][0] = f32x2{b, b};
        acc[g][1] = f32x2{b, b};
    }

#pragma unroll
    for (int h = 0; h < Hn; ++h) {
        u32 u0 = (u32)sv[h][0], u1 = (u32)sv[h][1];
        f32x2 v0, v1;
        v0[0] = __builtin_bit_cast(float, u0 << 16);
        v0[1] = __builtin_bit_cast(float, u0 & 0xffff0000u);
        v1[0] = __builtin_bit_cast(float, u1 << 16);
        v1[1] = __builtin_bit_cast(float, u1 & 0xffff0000u);
#pragma unroll
        for (int g = 0; g < Hn; ++g) {
            float w = w1[h * Hn + g];
            f32x2 wv = {w, w};
            acc[g][0] += wv * v0;
            acc[g][1] += wv * v1;
        }
    }

    // exp2 + row-sum
    float sm[Hn];
#pragma unroll
    for (int g = 0; g < Hn; ++g) {
        acc[g][0][0] = EXP2(acc[g][0][0]);
        acc[g][0][1] = EXP2(acc[g][0][1]);
        acc[g][1][0] = EXP2(acc[g][1][0]);
        acc[g][1][1] = EXP2(acc[g][1][1]);
        f32x2 s2 = acc[g][0] + acc[g][1];
        sm[g] = s2[0] + s2[1];
    }
#pragma unroll
    for (int off = 32; off; off >>= 1)
#pragma unroll
        for (int g = 0; g < Hn; ++g) sm[g] += __shfl_xor(sm[g], off, 64);
    int wv2 = tid >> 6, ln = tid & 63;
    if (ln < Hn) redS[wv2][ln] = sm[ln];
    __syncthreads();
#pragma unroll
    for (int g = 0; g < Hn; ++g) {
        float inv = RCP(redS[0][g] + redS[1][g] + redS[2][g] + redS[3][g]);
        f32x2 iv = {inv, inv};
        acc[g][0] *= iv;
        acc[g][1] *= iv;
    }

    // mix2 (f32x2) + RNE-packed store: out[g] = b2[g] + sum_h w2[g,h] * P[h]
#pragma unroll
    for (int g = 0; g < Hn; ++g) {
        float b = b2v[g];
        f32x2 o0 = {b, b}, o1 = {b, b};
#pragma unroll
        for (int h = 0; h < Hn; ++h) {
            float w = w2[h * Hn + g];
            f32x2 wv = {w, w};
            o0 += wv * acc[h][0];
            o1 += wv * acc[h][1];
        }
        i32x2 ob;
        ob[0] = (int)bfpack(o0[0], o0[1]);
        ob[1] = (int)bfpack(o1[0], o1[1]);
        *reinterpret_cast<i32x2*>(&S[base0 + g * Nn]) = ob;
    }
}

// ---------------- V transpose: Vt[b][g][d=64][m=1024] = QKV[b*Nn+m][VOFF+g*64+d] ----------------
__global__ __launch_bounds__(256) void vtrans_kernel(const u16* __restrict__ QKV,
                                                     u16* __restrict__ Vt) {
    __shared__ u16 lT[64 * 64];
    int bg = blockIdx.y, g = bg % Hn, b = bg / Hn;
    int m0 = blockIdx.x * 64;
    int tid = threadIdx.x;

    int r = tid >> 3, d8 = tid & 7;
#pragma unroll
    for (int p = 0; p < 2; ++p) {
        int rr = r + p * 32;
        i32x4 v = *reinterpret_cast<const i32x4*>(
            &QKV[((size_t)(b * Nn) + m0 + rr) * LDQ + VOFF + g * 64 + d8 * 8]);
        *reinterpret_cast<i32x4*>(&lT[rr * 64 + ((d8 ^ (rr & 7)) * 8)]) = v;
    }
    __syncthreads();

    int d = tid >> 3, rs = (tid & 7) * 8;
#pragma unroll
    for (int p = 0; p < 2; ++p) {
        int dd = d + p * 32;
        u16 o[8];
#pragma unroll
        for (int j = 0; j < 8; ++j)
            o[j] = lT[(rs + j) * 64 + (((dd >> 3) ^ j) * 8) + (dd & 7)];
        *reinterpret_cast<i32x4*>(&Vt[((size_t)(b * Hn + g) * 64 + dd) * Nn + m0 + rs]) =
            *reinterpret_cast<const i32x4*>(o);
    }
}

// ---------------- PV as NT GEMM: tile 64n x 64d, BK=32 over m ----------------
// 64-tile keeps grid at 384 blocks with conc=2. 2-phase dbuf + seg-swizzle +
// XCD block swizzle.
__global__ __launch_bounds__(256) void pv_kernel(const u16* __restrict__ S,
                                                 const u16* __restrict__ Vt,
                                                 u16* __restrict__ O, int b0) {
    __shared__ u16 lA[2][64 * 32];
    __shared__ u16 lB[2][64 * 32];
    int tid = threadIdx.x, wave = tid >> 6, lane = tid & 63;

    int nwg = gridDim.x * gridDim.y;
    int bid = blockIdx.y * gridDim.x + blockIdx.x;
    if ((nwg & 7) == 0) {
        int cpx = nwg >> 3;
        bid = (bid & 7) * cpx + (bid >> 3);
    }
    int zz = bid / gridDim.x, g = zz % Hn, bb = zz / Hn, b = b0 + bb;
    int n0 = (bid % gridDim.x) * 64;

    f32x4 acc[4] = {};
    int sseg = (tid & 3) ^ ((tid >> 3) & 3);
    const u16* gA = S + sidx(bb, n0 + (tid >> 2), g) + sseg * 8;
    const u16* gB = Vt + ((size_t)(b * Hn + g) * 64 + (tid >> 2)) * Nn + sseg * 8;

    auto stage = [&](int buf, int m0) {
        gload16(gA + m0, &lA[buf][tid * 8]);
        gload16(gB + m0, &lB[buf][tid * 8]);
    };

    int sw8 = (((lane >> 4) ^ ((lane >> 1) & 3))) * 8;

    stage(0, 0);
    __syncthreads();

    int cur = 0;
    for (int t = 0; t < Nn / 32; ++t) {
        if (t + 1 < Nn / 32) stage(cur ^ 1, (t + 1) * 32);

        short8 af = *reinterpret_cast<const short8*>(
            &lA[cur][(wave * 16 + (lane & 15)) * 32 + sw8]);
#pragma unroll
        for (int c = 0; c < 4; ++c) {
            short8 bf = *reinterpret_cast<const short8*>(
                &lB[cur][(c * 16 + (lane & 15)) * 32 + sw8]);
            acc[c] = __builtin_amdgcn_mfma_f32_16x16x32_bf16(af, bf, acc[c], 0, 0, 0);
        }

        __syncthreads();
        cur ^= 1;
    }

    int orow = n0 + wave * 16 + (lane >> 4) * 4;
#pragma unroll
    for (int c = 0; c < 4; ++c) {
        int ocol = g * 64 + c * 16 + (lane & 15);
#pragma unroll
        for (int r = 0; r < 4; ++r)
            O[((size_t)(b * Nn) + orow + r) * Dn + ocol] = f2bf(acc[c][r]);
    }
}

// ---------------- launch ----------------
extern "C" void kernel_launch(void* const* d_in, const int* in_sizes, int n_in,
                              void* d_out, int out_size, void* d_ws, size_t ws_size,
                              hipStream_t stream) {
    const float* x    = (const float*)d_in[0];
    const float* wq   = (const float*)d_in[1];
    const float* bq   = (const float*)d_in[2];
    const float* wk   = (const float*)d_in[3];
    const float* bk   = (const float*)d_in[4];
    const float* wv   = (const float*)d_in[5];
    const float* bv   = (const float*)d_in[6];
    const float* wo   = (const float*)d_in[7];
    const float* bo   = (const float*)d_in[8];
    const float* th1w = (const float*)d_in[9];
    const float* th1b = (const float*)d_in[10];
    const float* th2w = (const float*)d_in[11];
    const float* th2b = (const float*)d_in[12];

    size_t off = 0;
    auto alloc = [&](size_t bytes) {
        void* p = (char*)d_ws + off;
        off += (bytes + 255) & ~(size_t)255;
        return p;
    };
    const size_t RD2 = (size_t)Rn * Dn * 2;
    const size_t DD = (size_t)Dn * Dn;
    u16*   xb    = (u16*)alloc(RD2);               // x bf16; reused as PV output O
    u16*   qkvb  = (u16*)alloc((size_t)Rn * LDQ * 2);  // merged [Q|K|V] 8192x2304
    u16*   vtb   = (u16*)alloc(RD2);               // V transposed [b][g][64][1024]
    u16*   wqkvb = (u16*)alloc(3 * DD * 2);        // [wq;wk;wv] contiguous
    u16*   wob   = (u16*)alloc(DD * 2);
    float* bqkv  = (float*)alloc(3 * Dn * 4);      // [bq|bk|bv]

    const size_t SB = (size_t)Hn * Nn * Nn * 2;    // one batch of scores
    size_t base = off;
    int conc = 1;
    if (ws_size > base + SB) {
        size_t c = (ws_size - base) / SB;
        conc = c > 2 ? 2 : (int)c;            // cap 2: S slice (50MB) fully L3-resident
    }
    u16* sb = (u16*)((char*)d_ws + base);

    // converts
    cvt4_kernel<<<(Rn * Dn / 4 + 255) / 256, 256, 0, stream>>>(x, xb, Rn * Dn / 4);
    cvtw_kernel<<<dim3((Dn * Dn / 4 + 255) / 256, 4), 256, 0, stream>>>(
        wq, wk, wv, wo, wqkvb, wqkvb + DD, wqkvb + 2 * DD, wob, Dn * Dn / 4);
    bcat_kernel<<<(3 * Dn + 255) / 256, 256, 0, stream>>>(bq, bk, bv, bqkv);

    // merged QKV projection: 8192 x 2304 x 768
    gemm128<true><<<dim3(LDQ / 128, Rn / 128), 256, 0, stream>>>(
        xb, wqkvb, bqkv, qkvb, Rn, LDQ, Dn);

    // V transpose (all batches)
    vtrans_kernel<<<dim3(Nn / 64, Bn * Hn), 256, 0, stream>>>(qkvb, vtb);

    // attention core, conc batches at a time; PV output goes into xb (free now)
    for (int b0 = 0; b0 < Bn; b0 += conc) {
        int g = (Bn - b0) < conc ? (Bn - b0) : conc;
        qk_kernel<<<dim3(Nn / 64, Nn / 64, (Hn / HPB) * g), 256, 0, stream>>>(qkvb, sb, b0);
        mid_kernel<<<g * Nn, 256, 0, stream>>>(sb, th1w, th1b, th2w, th2b);
        pv_kernel<<<dim3(Nn / 64, Hn * g), 256, 0, stream>>>(sb, vtb, xb, b0);
    }

    // final projection -> f32 out
    gemm128<false><<<dim3(Dn / 128, Rn / 128), 256, 0, stream>>>(
        xb, wob, bo, d_out, Rn, Dn, Dn);
}

// Round 15
// 291.852 us; speedup vs baseline: 1.2121x; 1.2121x over previous
//
#include <hip/hip_runtime.h>
#include <hip/hip_bf16.h>

typedef __attribute__((ext_vector_type(8))) short short8;   // bf16x8 (4 VGPR)
typedef __attribute__((ext_vector_type(4))) float f32x4;
typedef __attribute__((ext_vector_type(2))) float f32x2;
typedef __attribute__((ext_vector_type(4))) int i32x4;
typedef __attribute__((ext_vector_type(2))) int i32x2;

typedef unsigned short u16;
typedef unsigned int u32;

#define DEVI static __device__ __forceinline__

constexpr int Bn = 8, Nn = 1024, Dn = 768, Hn = 12;
constexpr int Rn = Bn * Nn;                 // 8192 rows
constexpr int LDQ = 3 * Dn;                 // merged QKV row stride (2304)
constexpr int KOFF = Dn, VOFF = 2 * Dn;     // K/V column offsets in QKV
constexpr float SCALE = 0.125f;             // (768/12)^-0.5 = 1/8
constexpr float LOG2E = 1.44269504088896340736f;
constexpr int HPB = 4;                      // heads per qk block (12 = 3 groups)

// S scratch layout: [bb][n][h][m]  (h-interleaved: one (b,n) row's 12 heads
// are a contiguous 24KB slab -> mid_kernel streams, L2/L3 friendly)
DEVI size_t sidx(int bb, int n, int h) {
    return (((size_t)bb * Nn + n) * Hn + h) * Nn;
}

DEVI u16 f2bf(float f) {
    __hip_bfloat16 h = __float2bfloat16(f);
    return __builtin_bit_cast(u16, h);
}

// RNE bf16 pack of two floats (bit-identical to __float2bfloat16 for finite x)
DEVI u32 bfpack(float a, float b) {
    u32 xa = __builtin_bit_cast(u32, a);
    u32 xb = __builtin_bit_cast(u32, b);
    xa += 0x7fffu + ((xa >> 16) & 1u);
    xb += 0x7fffu + ((xb >> 16) & 1u);
    return (xa >> 16) | (xb & 0xffff0000u);
}

#if __has_builtin(__builtin_amdgcn_exp2f)
#define EXP2(x) __builtin_amdgcn_exp2f(x)
#else
#define EXP2(x) exp2f(x)
#endif
#if __has_builtin(__builtin_amdgcn_rcpf)
#define RCP(x) __builtin_amdgcn_rcpf(x)
#else
#define RCP(x) (1.0f / (x))
#endif

// async global->LDS, 16B per lane; LDS dest must be wave-uniform base + lane*16
DEVI void gload16(const u16* g, u16* l) {
    __builtin_amdgcn_global_load_lds(
        (const __attribute__((address_space(1))) void*)g,
        (__attribute__((address_space(3))) void*)l,
        16, 0, 0);
}

// ---------------- f32 -> bf16 convert, 4 elems/thread ----------------
__global__ __launch_bounds__(256) void cvt4_kernel(const float* __restrict__ in,
                                                   u16* __restrict__ out, int n4) {
    int i = blockIdx.x * 256 + threadIdx.x;
    if (i >= n4) return;
    f32x4 v = *reinterpret_cast<const f32x4*>(&in[(size_t)i * 4]);
    u16 o[4];
#pragma unroll
    for (int j = 0; j < 4; ++j) o[j] = f2bf(v[j]);
    *reinterpret_cast<u32*>(&out[(size_t)i * 4]) = (u32)o[0] | ((u32)o[1] << 16);
    *reinterpret_cast<u32*>(&out[(size_t)i * 4 + 2]) = (u32)o[2] | ((u32)o[3] << 16);
}

// 4 weight matrices (same size) in one launch; blockIdx.y selects the matrix
__global__ __launch_bounds__(256) void cvtw_kernel(const float* __restrict__ a,
                                                   const float* __restrict__ b,
                                                   const float* __restrict__ c,
                                                   const float* __restrict__ d,
                                                   u16* oa, u16* ob, u16* oc, u16* od,
                                                   int n4) {
    int i = blockIdx.x * 256 + threadIdx.x;
    if (i >= n4) return;
    const float* in; u16* out;
    switch (blockIdx.y) {
        case 0: in = a; out = oa; break;
        case 1: in = b; out = ob; break;
        case 2: in = c; out = oc; break;
        default: in = d; out = od; break;
    }
    f32x4 v = *reinterpret_cast<const f32x4*>(&in[(size_t)i * 4]);
    u16 o[4];
#pragma unroll
    for (int j = 0; j < 4; ++j) o[j] = f2bf(v[j]);
    *reinterpret_cast<u32*>(&out[(size_t)i * 4]) = (u32)o[0] | ((u32)o[1] << 16);
    *reinterpret_cast<u32*>(&out[(size_t)i * 4 + 2]) = (u32)o[2] | ((u32)o[3] << 16);
}

// concat 3 bias vectors of Dn floats -> one 3*Dn array
__global__ __launch_bounds__(256) void bcat_kernel(const float* __restrict__ a,
                                                   const float* __restrict__ b,
                                                   const float* __restrict__ c,
                                                   float* __restrict__ o) {
    int i = blockIdx.x * 256 + threadIdx.x;
    if (i < Dn) o[i] = a[i];
    else if (i < 2 * Dn) o[i] = b[i - Dn];
    else if (i < 3 * Dn) o[i] = c[i - 2 * Dn];
}

// ---------------- 128x128 NT GEMM: C[M,Nc] = A[M,K]*B[Nc,K]^T + bias ----------------
// r11 form (best measured): single-buffer, seg-swizzled LDS (conflict-free),
// XCD-aware block swizzle. 16KB LDS -> high co-residency.
template <bool BF16OUT>
__global__ __launch_bounds__(256) void gemm128(const u16* __restrict__ A,
                                               const u16* __restrict__ Bm,
                                               const float* __restrict__ bias,
                                               void* __restrict__ Cv,
                                               int M, int Nc, int K) {
    __shared__ u16 lA[128 * 32];
    __shared__ u16 lB[128 * 32];
    int tid = threadIdx.x, wave = tid >> 6, lane = tid & 63;
    int wr = (wave >> 1) * 64, wc = (wave & 1) * 64;

    int nwg = gridDim.x * gridDim.y;
    int bid = blockIdx.y * gridDim.x + blockIdx.x;
    if ((nwg & 7) == 0) {
        int cpx = nwg >> 3;
        bid = (bid & 7) * cpx + (bid >> 3);
    }
    int row0 = (bid / gridDim.x) * 128, col0 = (bid % gridDim.x) * 128;

    f32x4 acc[4][4] = {};

    // staging: LDS element (row=tid>>2, seg=tid&3); source seg pre-swizzled
    int sseg = (tid & 3) ^ ((tid >> 3) & 3);
    const u16* gA = A + (size_t)(row0 + (tid >> 2)) * K + sseg * 8;
    const u16* gB = Bm + (size_t)(col0 + (tid >> 2)) * K + sseg * 8;
    u16* sA = &lA[tid * 8];
    u16* sB = &lB[tid * 8];

    // fragment-read seg swizzle: (row>>1)&3 == ((lane&15)>>1)&3 (wave-uniform rest)
    int sw8 = (((lane >> 4) ^ ((lane >> 1) & 3))) * 8;

    for (int k0 = 0; k0 < K; k0 += 32) {
        gload16(gA + k0, sA);
        gload16(gA + k0 + (size_t)64 * K, sA + 2048);
        gload16(gB + k0, sB);
        gload16(gB + k0 + (size_t)64 * K, sB + 2048);
        __syncthreads();

        short8 af[4], bf[4];
#pragma unroll
        for (int a = 0; a < 4; ++a)
            af[a] = *reinterpret_cast<const short8*>(
                &lA[(wr + a * 16 + (lane & 15)) * 32 + sw8]);
#pragma unroll
        for (int c = 0; c < 4; ++c)
            bf[c] = *reinterpret_cast<const short8*>(
                &lB[(wc + c * 16 + (lane & 15)) * 32 + sw8]);
#pragma unroll
        for (int a = 0; a < 4; ++a)
#pragma unroll
            for (int c = 0; c < 4; ++c)
                acc[a][c] = __builtin_amdgcn_mfma_f32_16x16x32_bf16(af[a], bf[c], acc[a][c], 0, 0, 0);
        __syncthreads();
    }

#pragma unroll
    for (int a = 0; a < 4; ++a) {
        int crow = row0 + wr + a * 16 + (lane >> 4) * 4;
#pragma unroll
        for (int c = 0; c < 4; ++c) {
            int col = col0 + wc + c * 16 + (lane & 15);
            float bv = bias ? bias[col] : 0.f;
#pragma unroll
            for (int r = 0; r < 4; ++r) {
                float v = acc[a][c][r] + bv;
                if (BF16OUT)
                    reinterpret_cast<u16*>(Cv)[(size_t)(crow + r) * Nc + col] = f2bf(v);
                else
                    reinterpret_cast<float*>(Cv)[(size_t)(crow + r) * Nc + col] = v;
            }
        }
    }
}

// ---------------- batched QK^T, HPB=4 heads per block ----------------
// Stage Q[64n x 256] and K[64m x 256] (4 contiguous head-bands) once -> 64KB LDS,
// compute 4 head-tiles (128 MFMA/block). Row = 256 elems (512B); seg-swizzle
// seg^=(row&7) via pre-swizzled gload source + swizzled read (2-way, free).
__global__ __launch_bounds__(256) void qk_kernel(const u16* __restrict__ QKV,
                                                 u16* __restrict__ S, int b0) {
    __shared__ u16 lQ[64 * 64 * HPB];
    __shared__ u16 lK[64 * 64 * HPB];
    int z = blockIdx.z, hg = z % (Hn / HPB), bb = z / (Hn / HPB), b = b0 + bb;
    int h0 = hg * HPB;
    int n0 = blockIdx.y * 64, m0 = blockIdx.x * 64;
    int tid = threadIdx.x, wave = tid >> 6, lane = tid & 63;

    // stage: chunk c = i*256 + tid; row = c>>5, seg = c&31; source col pre-swizzled
    {
        int seg = tid & 31;
#pragma unroll
        for (int i = 0; i < 8; ++i) {
            int row = i * 8 + (tid >> 5);
            int scol = (seg ^ (row & 7)) * 8;
            const u16* gQ = QKV + ((size_t)(b * Nn) + n0 + row) * LDQ + h0 * 64 + scol;
            const u16* gK = QKV + ((size_t)(b * Nn) + m0 + row) * LDQ + KOFF + h0 * 64 + scol;
            gload16(gQ, &lQ[i * 2048 + tid * 8]);
            gload16(gK, &lK[i * 2048 + tid * 8]);
        }
    }
    __syncthreads();

    f32x4 acc[HPB][4] = {};
#pragma unroll
    for (int hh = 0; hh < HPB; ++hh) {
#pragma unroll
        for (int kk = 0; kk < 2; ++kk) {
            int segd = hh * 8 + kk * 4 + (lane >> 4);      // desired 16B seg in row
            int rK = wave * 16 + (lane & 15);
            short8 bf = *reinterpret_cast<const short8*>(
                &lK[rK * 256 + ((segd ^ (rK & 7)) * 8)]);
#pragma unroll
            for (int a = 0; a < 4; ++a) {
                int rQ = a * 16 + (lane & 15);
                short8 af = *reinterpret_cast<const short8*>(
                    &lQ[rQ * 256 + ((segd ^ (rQ & 7)) * 8)]);
                acc[hh][a] = __builtin_amdgcn_mfma_f32_16x16x32_bf16(af, bf, acc[hh][a], 0, 0, 0);
            }
        }
    }

    int col = m0 + wave * 16 + (lane & 15);
#pragma unroll
    for (int hh = 0; hh < HPB; ++hh)
#pragma unroll
        for (int a = 0; a < 4; ++a) {
            int rowb = n0 + a * 16 + (lane >> 4) * 4;
#pragma unroll
            for (int r = 0; r < 4; ++r)
                S[sidx(bb, rowb + r, h0 + hh) + col] = f2bf(acc[hh][a][r] * SCALE);
        }
}

// ---------------- fused mix1 + softmax + mix2 (in place on S) ----------------
// R8 form (proven best): one block (256 thr) per (bb, n) row; 4 m-positions per
// thread. f32x2 vector math, raw v_exp_f32, v_rcp_f32, manual RNE pack.
// No max-subtraction: |logits| bounded, f32 exp cannot overflow.
__global__ __launch_bounds__(256) void mid_kernel(u16* __restrict__ S,
                                                  const float* __restrict__ w1p,
                                                  const float* __restrict__ b1p,
                                                  const float* __restrict__ w2p,
                                                  const float* __restrict__ b2p) {
    __shared__ float w1[Hn * Hn], w2[Hn * Hn], b1v[Hn], b2v[Hn];
    __shared__ float redS[4][Hn];
    int tid = threadIdx.x;
    for (int i = tid; i < Hn * Hn; i += 256) {
        int g = i % Hn, h = i / Hn;           // store transposed: w[h][g]
        w1[i] = w1p[g * Hn + h] * LOG2E;      // exp2-direct prescale
        w2[i] = w2p[g * Hn + h];
    }
    if (tid < Hn) { b1v[tid] = b1p[tid] * LOG2E; b2v[tid] = b2p[tid]; }
    __syncthreads();

    int bb = blockIdx.x >> 10, n = blockIdx.x & 1023;
    size_t base0 = sidx(bb, n, 0) + tid * 4;      // + h*Nn per head plane

    // prefetch ALL 12 head slabs (12 outstanding dwordx2 loads, one wait)
    i32x2 sv[Hn];
#pragma unroll
    for (int h = 0; h < Hn; ++h)
        sv[h] = *reinterpret_cast<const i32x2*>(&S[base0 + h * Nn]);

    // mix1 (f32x2): acc[g] = b1s[g] + sum_h w1s[g,h] * S[h]   (log2-scaled)
    f32x2 acc[Hn][2];
#pragma unroll
    for (int g = 0; g < Hn; ++g) {
        float b = b1v[g];
        acc[g][0] = f32x2{b, b};
        acc[g][1] = f32x2{b, b};
    }

#pragma unroll
    for (int h = 0; h < Hn; ++h) {
        u32 u0 = (u32)sv[h][0], u1 = (u32)sv[h][1];
        f32x2 v0, v1;
        v0[0] = __builtin_bit_cast(float, u0 << 16);
        v0[1] = __builtin_bit_cast(float, u0 & 0xffff0000u);
        v1[0] = __builtin_bit_cast(float, u1 << 16);
        v1[1] = __builtin_bit_cast(float, u1 & 0xffff0000u);
#pragma unroll
        for (int g = 0; g < Hn; ++g) {
            float w = w1[h * Hn + g];
            f32x2 wv = {w, w};
            acc[g][0] += wv * v0;
            acc[g][1] += wv * v1;
        }
    }

    // exp2 + row-sum
    float sm[Hn];
#pragma unroll
    for (int g = 0; g < Hn; ++g) {
        acc[g][0][0] = EXP2(acc[g][0][0]);
        acc[g][0][1] = EXP2(acc[g][0][1]);
        acc[g][1][0] = EXP2(acc[g][1][0]);
        acc[g][1][1] = EXP2(acc[g][1][1]);
        f32x2 s2 = acc[g][0] + acc[g][1];
        sm[g] = s2[0] + s2[1];
    }
#pragma unroll
    for (int off = 32; off; off >>= 1)
#pragma unroll
        for (int g = 0; g < Hn; ++g) sm[g] += __shfl_xor(sm[g], off, 64);
    int wv2 = tid >> 6, ln = tid & 63;
    if (ln < Hn) redS[wv2][ln] = sm[ln];
    __syncthreads();
#pragma unroll
    for (int g = 0; g < Hn; ++g) {
        float inv = RCP(redS[0][g] + redS[1][g] + redS[2][g] + redS[3][g]);
        f32x2 iv = {inv, inv};
        acc[g][0] *= iv;
        acc[g][1] *= iv;
    }

    // mix2 (f32x2) + RNE-packed store: out[g] = b2[g] + sum_h w2[g,h] * P[h]
#pragma unroll
    for (int g = 0; g < Hn; ++g) {
        float b = b2v[g];
        f32x2 o0 = {b, b}, o1 = {b, b};
#pragma unroll
        for (int h = 0; h < Hn; ++h) {
            float w = w2[h * Hn + g];
            f32x2 wv = {w, w};
            o0 += wv * acc[h][0];
            o1 += wv * acc[h][1];
        }
        i32x2 ob;
        ob[0] = (int)bfpack(o0[0], o0[1]);
        ob[1] = (int)bfpack(o1[0], o1[1]);
        *reinterpret_cast<i32x2*>(&S[base0 + g * Nn]) = ob;
    }
}

// ---------------- V transpose: Vt[b][g][d=64][m=1024] = QKV[b*Nn+m][VOFF+g*64+d] ----------------
__global__ __launch_bounds__(256) void vtrans_kernel(const u16* __restrict__ QKV,
                                                     u16* __restrict__ Vt) {
    __shared__ u16 lT[64 * 64];
    int bg = blockIdx.y, g = bg % Hn, b = bg / Hn;
    int m0 = blockIdx.x * 64;
    int tid = threadIdx.x;

    int r = tid >> 3, d8 = tid & 7;
#pragma unroll
    for (int p = 0; p < 2; ++p) {
        int rr = r + p * 32;
        i32x4 v = *reinterpret_cast<const i32x4*>(
            &QKV[((size_t)(b * Nn) + m0 + rr) * LDQ + VOFF + g * 64 + d8 * 8]);
        *reinterpret_cast<i32x4*>(&lT[rr * 64 + ((d8 ^ (rr & 7)) * 8)]) = v;
    }
    __syncthreads();

    int d = tid >> 3, rs = (tid & 7) * 8;
#pragma unroll
    for (int p = 0; p < 2; ++p) {
        int dd = d + p * 32;
        u16 o[8];
#pragma unroll
        for (int j = 0; j < 8; ++j)
            o[j] = lT[(rs + j) * 64 + (((dd >> 3) ^ j) * 8) + (dd & 7)];
        *reinterpret_cast<i32x4*>(&Vt[((size_t)(b * Hn + g) * 64 + dd) * Nn + m0 + rs]) =
            *reinterpret_cast<const i32x4*>(o);
    }
}

// ---------------- PV as NT GEMM: tile 128n x 64d, BK=32 over m ----------------
// r11 form: single-buffer, seg-swizzled LDS, XCD block swizzle, 384 blocks @conc=4
__global__ __launch_bounds__(256) void pv_kernel(const u16* __restrict__ S,
                                                 const u16* __restrict__ Vt,
                                                 u16* __restrict__ O, int b0) {
    __shared__ u16 lA[128 * 32];
    __shared__ u16 lB[64 * 32];
    int tid = threadIdx.x, wave = tid >> 6, lane = tid & 63;

    int nwg = gridDim.x * gridDim.y;
    int bid = blockIdx.y * gridDim.x + blockIdx.x;
    if ((nwg & 7) == 0) {
        int cpx = nwg >> 3;
        bid = (bid & 7) * cpx + (bid >> 3);
    }
    int zz = bid / gridDim.x, g = zz % Hn, bb = zz / Hn, b = b0 + bb;
    int n0 = (bid % gridDim.x) * 128;

    constexpr size_t RS = (size_t)Hn * Nn;        // S row stride (n -> n+1)
    f32x4 acc[2][4] = {};
    int sseg = (tid & 3) ^ ((tid >> 3) & 3);
    const u16* gA = S + sidx(bb, n0 + (tid >> 2), g) + sseg * 8;
    const u16* gB = Vt + ((size_t)(b * Hn + g) * 64 + (tid >> 2)) * Nn + sseg * 8;
    u16* sA = &lA[tid * 8];
    u16* sB = &lB[tid * 8];

    int sw8 = (((lane >> 4) ^ ((lane >> 1) & 3))) * 8;

    for (int m0 = 0; m0 < Nn; m0 += 32) {
        gload16(gA + m0, sA);
        gload16(gA + m0 + 64 * RS, sA + 2048);
        gload16(gB + m0, sB);
        __syncthreads();

        short8 bf[4];
#pragma unroll
        for (int c = 0; c < 4; ++c)
            bf[c] = *reinterpret_cast<const short8*>(
                &lB[(c * 16 + (lane & 15)) * 32 + sw8]);
#pragma unroll
        for (int a = 0; a < 2; ++a) {
            short8 af = *reinterpret_cast<const short8*>(
                &lA[(wave * 32 + a * 16 + (lane & 15)) * 32 + sw8]);
#pragma unroll
            for (int c = 0; c < 4; ++c)
                acc[a][c] = __builtin_amdgcn_mfma_f32_16x16x32_bf16(af, bf[c], acc[a][c], 0, 0, 0);
        }
        __syncthreads();
    }

#pragma unroll
    for (int a = 0; a < 2; ++a) {
        int orow = n0 + wave * 32 + a * 16 + (lane >> 4) * 4;
#pragma unroll
        for (int c = 0; c < 4; ++c) {
            int ocol = g * 64 + c * 16 + (lane & 15);
#pragma unroll
            for (int r = 0; r < 4; ++r)
                O[((size_t)(b * Nn) + orow + r) * Dn + ocol] = f2bf(acc[a][c][r]);
        }
    }
}

// ---------------- launch ----------------
extern "C" void kernel_launch(void* const* d_in, const int* in_sizes, int n_in,
                              void* d_out, int out_size, void* d_ws, size_t ws_size,
                              hipStream_t stream) {
    const float* x    = (const float*)d_in[0];
    const float* wq   = (const float*)d_in[1];
    const float* bq   = (const float*)d_in[2];
    const float* wk   = (const float*)d_in[3];
    const float* bk   = (const float*)d_in[4];
    const float* wv   = (const float*)d_in[5];
    const float* bv   = (const float*)d_in[6];
    const float* wo   = (const float*)d_in[7];
    const float* bo   = (const float*)d_in[8];
    const float* th1w = (const float*)d_in[9];
    const float* th1b = (const float*)d_in[10];
    const float* th2w = (const float*)d_in[11];
    const float* th2b = (const float*)d_in[12];

    size_t off = 0;
    auto alloc = [&](size_t bytes) {
        void* p = (char*)d_ws + off;
        off += (bytes + 255) & ~(size_t)255;
        return p;
    };
    const size_t RD2 = (size_t)Rn * Dn * 2;
    const size_t DD = (size_t)Dn * Dn;
    u16*   xb    = (u16*)alloc(RD2);               // x bf16; reused as PV output O
    u16*   qkvb  = (u16*)alloc((size_t)Rn * LDQ * 2);  // merged [Q|K|V] 8192x2304
    u16*   vtb   = (u16*)alloc(RD2);               // V transposed [b][g][64][1024]
    u16*   wqkvb = (u16*)alloc(3 * DD * 2);        // [wq;wk;wv] contiguous
    u16*   wob   = (u16*)alloc(DD * 2);
    float* bqkv  = (float*)alloc(3 * Dn * 4);      // [bq|bk|bv]

    const size_t SB = (size_t)Hn * Nn * Nn * 2;    // one batch of scores
    size_t base = off;
    int conc = 1;
    if (ws_size > base + SB) {
        size_t c = (ws_size - base) / SB;
        conc = c > 4 ? 4 : (int)c;            // cap 4 (best measured: r11)
    }
    u16* sb = (u16*)((char*)d_ws + base);

    // converts
    cvt4_kernel<<<(Rn * Dn / 4 + 255) / 256, 256, 0, stream>>>(x, xb, Rn * Dn / 4);
    cvtw_kernel<<<dim3((Dn * Dn / 4 + 255) / 256, 4), 256, 0, stream>>>(
        wq, wk, wv, wo, wqkvb, wqkvb + DD, wqkvb + 2 * DD, wob, Dn * Dn / 4);
    bcat_kernel<<<(3 * Dn + 255) / 256, 256, 0, stream>>>(bq, bk, bv, bqkv);

    // merged QKV projection: 8192 x 2304 x 768
    gemm128<true><<<dim3(LDQ / 128, Rn / 128), 256, 0, stream>>>(
        xb, wqkvb, bqkv, qkvb, Rn, LDQ, Dn);

    // V transpose (all batches)
    vtrans_kernel<<<dim3(Nn / 64, Bn * Hn), 256, 0, stream>>>(qkvb, vtb);

    // attention core, conc batches at a time; PV output goes into xb (free now)
    for (int b0 = 0; b0 < Bn; b0 += conc) {
        int g = (Bn - b0) < conc ? (Bn - b0) : conc;
        qk_kernel<<<dim3(Nn / 64, Nn / 64, (Hn / HPB) * g), 256, 0, stream>>>(qkvb, sb, b0);
        mid_kernel<<<g * Nn, 256, 0, stream>>>(sb, th1w, th1b, th2w, th2b);
        pv_kernel<<<dim3(Nn / 128, Hn * g), 256, 0, stream>>>(sb, vtb, xb, b0);
    }

    // final projection -> f32 out
    gemm128<false><<<dim3(Dn / 128, Rn / 128), 256, 0, stream>>>(
        xb, wob, bo, d_out, Rn, Dn, Dn);
}

// Round 16
// 279.724 us; speedup vs baseline: 1.2647x; 1.0434x over previous
//
#include <hip/hip_runtime.h>
#include <hip/hip_bf16.h>

typedef __attribute__((ext_vector_type(8))) short short8;   // bf16x8 (4 VGPR)
typedef __attribute__((ext_vector_type(4))) float f32x4;
typedef __attribute__((ext_vector_type(2))) float f32x2;
typedef __attribute__((ext_vector_type(4))) int i32x4;
typedef __attribute__((ext_vector_type(2))) int i32x2;

typedef unsigned short u16;
typedef unsigned int u32;

#define DEVI static __device__ __forceinline__

constexpr int Bn = 8, Nn = 1024, Dn = 768, Hn = 12;
constexpr int Rn = Bn * Nn;                 // 8192 rows
constexpr int LDQ = 3 * Dn;                 // merged QKV row stride (2304)
constexpr int KOFF = Dn, VOFF = 2 * Dn;     // K/V column offsets in QKV
constexpr float SCALE = 0.125f;             // (768/12)^-0.5 = 1/8
constexpr float LOG2E = 1.44269504088896340736f;
constexpr int HPB = 4;                      // heads per qk block (12 = 3 groups)

// S scratch layout: [bb][n][h][m]  (h-interleaved: one (b,n) row's 12 heads
// are a contiguous 24KB slab -> mid_kernel streams, L2/L3 friendly)
DEVI size_t sidx(int bb, int n, int h) {
    return (((size_t)bb * Nn + n) * Hn + h) * Nn;
}

DEVI u16 f2bf(float f) {
    __hip_bfloat16 h = __float2bfloat16(f);
    return __builtin_bit_cast(u16, h);
}

// RNE bf16 pack of two floats (bit-identical to __float2bfloat16 for finite x)
DEVI u32 bfpack(float a, float b) {
    u32 xa = __builtin_bit_cast(u32, a);
    u32 xb = __builtin_bit_cast(u32, b);
    xa += 0x7fffu + ((xa >> 16) & 1u);
    xb += 0x7fffu + ((xb >> 16) & 1u);
    return (xa >> 16) | (xb & 0xffff0000u);
}

#if __has_builtin(__builtin_amdgcn_exp2f)
#define EXP2(x) __builtin_amdgcn_exp2f(x)
#else
#define EXP2(x) exp2f(x)
#endif
#if __has_builtin(__builtin_amdgcn_rcpf)
#define RCP(x) __builtin_amdgcn_rcpf(x)
#else
#define RCP(x) (1.0f / (x))
#endif

// async global->LDS, 16B per lane; LDS dest must be wave-uniform base + lane*16
DEVI void gload16(const u16* g, u16* l) {
    __builtin_amdgcn_global_load_lds(
        (const __attribute__((address_space(1))) void*)g,
        (__attribute__((address_space(3))) void*)l,
        16, 0, 0);
}

// ---------------- f32 -> bf16 convert, 4 elems/thread ----------------
__global__ __launch_bounds__(256) void cvt4_kernel(const float* __restrict__ in,
                                                   u16* __restrict__ out, int n4) {
    int i = blockIdx.x * 256 + threadIdx.x;
    if (i >= n4) return;
    f32x4 v = *reinterpret_cast<const f32x4*>(&in[(size_t)i * 4]);
    u16 o[4];
#pragma unroll
    for (int j = 0; j < 4; ++j) o[j] = f2bf(v[j]);
    *reinterpret_cast<u32*>(&out[(size_t)i * 4]) = (u32)o[0] | ((u32)o[1] << 16);
    *reinterpret_cast<u32*>(&out[(size_t)i * 4 + 2]) = (u32)o[2] | ((u32)o[3] << 16);
}

// 4 weight matrices (same size) in one launch; blockIdx.y selects the matrix
__global__ __launch_bounds__(256) void cvtw_kernel(const float* __restrict__ a,
                                                   const float* __restrict__ b,
                                                   const float* __restrict__ c,
                                                   const float* __restrict__ d,
                                                   u16* oa, u16* ob, u16* oc, u16* od,
                                                   int n4) {
    int i = blockIdx.x * 256 + threadIdx.x;
    if (i >= n4) return;
    const float* in; u16* out;
    switch (blockIdx.y) {
        case 0: in = a; out = oa; break;
        case 1: in = b; out = ob; break;
        case 2: in = c; out = oc; break;
        default: in = d; out = od; break;
    }
    f32x4 v = *reinterpret_cast<const f32x4*>(&in[(size_t)i * 4]);
    u16 o[4];
#pragma unroll
    for (int j = 0; j < 4; ++j) o[j] = f2bf(v[j]);
    *reinterpret_cast<u32*>(&out[(size_t)i * 4]) = (u32)o[0] | ((u32)o[1] << 16);
    *reinterpret_cast<u32*>(&out[(size_t)i * 4 + 2]) = (u32)o[2] | ((u32)o[3] << 16);
}

// concat 3 bias vectors of Dn floats -> one 3*Dn array
__global__ __launch_bounds__(256) void bcat_kernel(const float* __restrict__ a,
                                                   const float* __restrict__ b,
                                                   const float* __restrict__ c,
                                                   float* __restrict__ o) {
    int i = blockIdx.x * 256 + threadIdx.x;
    if (i < Dn) o[i] = a[i];
    else if (i < 2 * Dn) o[i] = b[i - Dn];
    else if (i < 3 * Dn) o[i] = c[i - 2 * Dn];
}

// ---------------- 128x128 NT GEMM, BK=64: C = A*B^T + bias ----------------
// 32 MFMA per barrier-round (12 rounds at K=768). Seg-swizzle for 64-elem rows:
// stored seg = (tid&7)^(row&7); read seg = segd^(lane&7). XCD block swizzle.
template <bool BF16OUT>
__global__ __launch_bounds__(256) void gemm128(const u16* __restrict__ A,
                                               const u16* __restrict__ Bm,
                                               const float* __restrict__ bias,
                                               void* __restrict__ Cv,
                                               int M, int Nc, int K) {
    __shared__ u16 lA[128 * 64];
    __shared__ u16 lB[128 * 64];
    int tid = threadIdx.x, wave = tid >> 6, lane = tid & 63;
    int wr = (wave >> 1) * 64, wc = (wave & 1) * 64;

    int nwg = gridDim.x * gridDim.y;
    int bid = blockIdx.y * gridDim.x + blockIdx.x;
    if ((nwg & 7) == 0) {
        int cpx = nwg >> 3;
        bid = (bid & 7) * cpx + (bid >> 3);
    }
    int row0 = (bid / gridDim.x) * 128, col0 = (bid % gridDim.x) * 128;

    f32x4 acc[4][4] = {};

    // staging: pass p covers rows p*32..p*32+31; row = p*32 + (tid>>3), seg = tid&7
    // source seg pre-swizzled: (tid&7) ^ (row&7) == (tid&7) ^ ((tid>>3)&7)
    int srow = tid >> 3;
    int sseg = (tid & 7) ^ (srow & 7);
    const u16* gA = A + (size_t)(row0 + srow) * K + sseg * 8;
    const u16* gB = Bm + (size_t)(col0 + srow) * K + sseg * 8;
    u16* sA = &lA[tid * 8];
    u16* sB = &lB[tid * 8];

    for (int k0 = 0; k0 < K; k0 += 64) {
        __syncthreads();          // prior reads done before overwrite
#pragma unroll
        for (int p = 0; p < 4; ++p) {
            gload16(gA + k0 + (size_t)(p * 32) * K, sA + p * 2048);
            gload16(gB + k0 + (size_t)(p * 32) * K, sB + p * 2048);
        }
        __syncthreads();          // staged data visible

#pragma unroll
        for (int kk = 0; kk < 2; ++kk) {
            int sw = ((kk * 4 + (lane >> 4)) ^ (lane & 7)) * 8;
            short8 af[4], bf[4];
#pragma unroll
            for (int a = 0; a < 4; ++a)
                af[a] = *reinterpret_cast<const short8*>(
                    &lA[(wr + a * 16 + (lane & 15)) * 64 + sw]);
#pragma unroll
            for (int c = 0; c < 4; ++c)
                bf[c] = *reinterpret_cast<const short8*>(
                    &lB[(wc + c * 16 + (lane & 15)) * 64 + sw]);
#pragma unroll
            for (int a = 0; a < 4; ++a)
#pragma unroll
                for (int c = 0; c < 4; ++c)
                    acc[a][c] = __builtin_amdgcn_mfma_f32_16x16x32_bf16(af[a], bf[c], acc[a][c], 0, 0, 0);
        }
    }

#pragma unroll
    for (int a = 0; a < 4; ++a) {
        int crow = row0 + wr + a * 16 + (lane >> 4) * 4;
#pragma unroll
        for (int c = 0; c < 4; ++c) {
            int col = col0 + wc + c * 16 + (lane & 15);
            float bv = bias ? bias[col] : 0.f;
#pragma unroll
            for (int r = 0; r < 4; ++r) {
                float v = acc[a][c][r] + bv;
                if (BF16OUT)
                    reinterpret_cast<u16*>(Cv)[(size_t)(crow + r) * Nc + col] = f2bf(v);
                else
                    reinterpret_cast<float*>(Cv)[(size_t)(crow + r) * Nc + col] = v;
            }
        }
    }
}

// ---------------- batched QK^T, HPB=4 heads per block ----------------
// Stage Q[64n x 256] and K[64m x 256] (4 contiguous head-bands) once -> 64KB LDS,
// compute 4 head-tiles (128 MFMA/block). Row = 256 elems (512B); seg-swizzle
// seg^=(row&7) via pre-swizzled gload source + swizzled read (2-way, free).
__global__ __launch_bounds__(256) void qk_kernel(const u16* __restrict__ QKV,
                                                 u16* __restrict__ S, int b0) {
    __shared__ u16 lQ[64 * 64 * HPB];
    __shared__ u16 lK[64 * 64 * HPB];
    int z = blockIdx.z, hg = z % (Hn / HPB), bb = z / (Hn / HPB), b = b0 + bb;
    int h0 = hg * HPB;
    int n0 = blockIdx.y * 64, m0 = blockIdx.x * 64;
    int tid = threadIdx.x, wave = tid >> 6, lane = tid & 63;

    // stage: chunk c = i*256 + tid; row = c>>5, seg = c&31; source col pre-swizzled
    {
        int seg = tid & 31;
#pragma unroll
        for (int i = 0; i < 8; ++i) {
            int row = i * 8 + (tid >> 5);
            int scol = (seg ^ (row & 7)) * 8;
            const u16* gQ = QKV + ((size_t)(b * Nn) + n0 + row) * LDQ + h0 * 64 + scol;
            const u16* gK = QKV + ((size_t)(b * Nn) + m0 + row) * LDQ + KOFF + h0 * 64 + scol;
            gload16(gQ, &lQ[i * 2048 + tid * 8]);
            gload16(gK, &lK[i * 2048 + tid * 8]);
        }
    }
    __syncthreads();

    f32x4 acc[HPB][4] = {};
#pragma unroll
    for (int hh = 0; hh < HPB; ++hh) {
#pragma unroll
        for (int kk = 0; kk < 2; ++kk) {
            int segd = hh * 8 + kk * 4 + (lane >> 4);      // desired 16B seg in row
            int rK = wave * 16 + (lane & 15);
            short8 bf = *reinterpret_cast<const short8*>(
                &lK[rK * 256 + ((segd ^ (rK & 7)) * 8)]);
#pragma unroll
            for (int a = 0; a < 4; ++a) {
                int rQ = a * 16 + (lane & 15);
                short8 af = *reinterpret_cast<const short8*>(
                    &lQ[rQ * 256 + ((segd ^ (rQ & 7)) * 8)]);
                acc[hh][a] = __builtin_amdgcn_mfma_f32_16x16x32_bf16(af, bf, acc[hh][a], 0, 0, 0);
            }
        }
    }

    int col = m0 + wave * 16 + (lane & 15);
#pragma unroll
    for (int hh = 0; hh < HPB; ++hh)
#pragma unroll
        for (int a = 0; a < 4; ++a) {
            int rowb = n0 + a * 16 + (lane >> 4) * 4;
#pragma unroll
            for (int r = 0; r < 4; ++r)
                S[sidx(bb, rowb + r, h0 + hh) + col] = f2bf(acc[hh][a][r] * SCALE);
        }
}

// ---------------- fused mix1 + softmax + mix2 (in place on S) ----------------
// R8 form (proven best): one block (256 thr) per (bb, n) row; 4 m-positions per
// thread. f32x2 vector math, raw v_exp_f32, v_rcp_f32, manual RNE pack.
// No max-subtraction: |logits| bounded, f32 exp cannot overflow.
__global__ __launch_bounds__(256) void mid_kernel(u16* __restrict__ S,
                                                  const float* __restrict__ w1p,
                                                  const float* __restrict__ b1p,
                                                  const float* __restrict__ w2p,
                                                  const float* __restrict__ b2p) {
    __shared__ float w1[Hn * Hn], w2[Hn * Hn], b1v[Hn], b2v[Hn];
    __shared__ float redS[4][Hn];
    int tid = threadIdx.x;
    for (int i = tid; i < Hn * Hn; i += 256) {
        int g = i % Hn, h = i / Hn;           // store transposed: w[h][g]
        w1[i] = w1p[g * Hn + h] * LOG2E;      // exp2-direct prescale
        w2[i] = w2p[g * Hn + h];
    }
    if (tid < Hn) { b1v[tid] = b1p[tid] * LOG2E; b2v[tid] = b2p[tid]; }
    __syncthreads();

    int bb = blockIdx.x >> 10, n = blockIdx.x & 1023;
    size_t base0 = sidx(bb, n, 0) + tid * 4;      // + h*Nn per head plane

    // prefetch ALL 12 head slabs (12 outstanding dwordx2 loads, one wait)
    i32x2 sv[Hn];
#pragma unroll
    for (int h = 0; h < Hn; ++h)
        sv[h] = *reinterpret_cast<const i32x2*>(&S[base0 + h * Nn]);

    // mix1 (f32x2): acc[g] = b1s[g] + sum_h w1s[g,h] * S[h]   (log2-scaled)
    f32x2 acc[Hn][2];
#pragma unroll
    for (int g = 0; g < Hn; ++g) {
        float b = b1v[g];
        acc[g][0] = f32x2{b, b};
        acc[g][1] = f32x2{b, b};
    }

#pragma unroll
    for (int h = 0; h < Hn; ++h) {
        u32 u0 = (u32)sv[h][0], u1 = (u32)sv[h][1];
        f32x2 v0, v1;
        v0[0] = __builtin_bit_cast(float, u0 << 16);
        v0[1] = __builtin_bit_cast(float, u0 & 0xffff0000u);
        v1[0] = __builtin_bit_cast(float, u1 << 16);
        v1[1] = __builtin_bit_cast(float, u1 & 0xffff0000u);
#pragma unroll
        for (int g = 0; g < Hn; ++g) {
            float w = w1[h * Hn + g];
            f32x2 wv = {w, w};
            acc[g][0] += wv * v0;
            acc[g][1] += wv * v1;
        }
    }

    // exp2 + row-sum
    float sm[Hn];
#pragma unroll
    for (int g = 0; g < Hn; ++g) {
        acc[g][0][0] = EXP2(acc[g][0][0]);
        acc[g][0][1] = EXP2(acc[g][0][1]);
        acc[g][1][0] = EXP2(acc[g][1][0]);
        acc[g][1][1] = EXP2(acc[g][1][1]);
        f32x2 s2 = acc[g][0] + acc[g][1];
        sm[g] = s2[0] + s2[1];
    }
#pragma unroll
    for (int off = 32; off; off >>= 1)
#pragma unroll
        for (int g = 0; g < Hn; ++g) sm[g] += __shfl_xor(sm[g], off, 64);
    int wv2 = tid >> 6, ln = tid & 63;
    if (ln < Hn) redS[wv2][ln] = sm[ln];
    __syncthreads();
#pragma unroll
    for (int g = 0; g < Hn; ++g) {
        float inv = RCP(redS[0][g] + redS[1][g] + redS[2][g] + redS[3][g]);
        f32x2 iv = {inv, inv};
        acc[g][0] *= iv;
        acc[g][1] *= iv;
    }

    // mix2 (f32x2) + RNE-packed store: out[g] = b2[g] + sum_h w2[g,h] * P[h]
#pragma unroll
    for (int g = 0; g < Hn; ++g) {
        float b = b2v[g];
        f32x2 o0 = {b, b}, o1 = {b, b};
#pragma unroll
        for (int h = 0; h < Hn; ++h) {
            float w = w2[h * Hn + g];
            f32x2 wv = {w, w};
            o0 += wv * acc[h][0];
            o1 += wv * acc[h][1];
        }
        i32x2 ob;
        ob[0] = (int)bfpack(o0[0], o0[1]);
        ob[1] = (int)bfpack(o1[0], o1[1]);
        *reinterpret_cast<i32x2*>(&S[base0 + g * Nn]) = ob;
    }
}

// ---------------- V transpose: Vt[b][g][d=64][m=1024] = QKV[b*Nn+m][VOFF+g*64+d] ----------------
__global__ __launch_bounds__(256) void vtrans_kernel(const u16* __restrict__ QKV,
                                                     u16* __restrict__ Vt) {
    __shared__ u16 lT[64 * 64];
    int bg = blockIdx.y, g = bg % Hn, b = bg / Hn;
    int m0 = blockIdx.x * 64;
    int tid = threadIdx.x;

    int r = tid >> 3, d8 = tid & 7;
#pragma unroll
    for (int p = 0; p < 2; ++p) {
        int rr = r + p * 32;
        i32x4 v = *reinterpret_cast<const i32x4*>(
            &QKV[((size_t)(b * Nn) + m0 + rr) * LDQ + VOFF + g * 64 + d8 * 8]);
        *reinterpret_cast<i32x4*>(&lT[rr * 64 + ((d8 ^ (rr & 7)) * 8)]) = v;
    }
    __syncthreads();

    int d = tid >> 3, rs = (tid & 7) * 8;
#pragma unroll
    for (int p = 0; p < 2; ++p) {
        int dd = d + p * 32;
        u16 o[8];
#pragma unroll
        for (int j = 0; j < 8; ++j)
            o[j] = lT[(rs + j) * 64 + (((dd >> 3) ^ j) * 8) + (dd & 7)];
        *reinterpret_cast<i32x4*>(&Vt[((size_t)(b * Hn + g) * 64 + dd) * Nn + m0 + rs]) =
            *reinterpret_cast<const i32x4*>(o);
    }
}

// ---------------- PV as NT GEMM: tile 128n x 64d, BK=64 over m ----------------
// 16 MFMA per barrier-round (16 rounds). Seg-swizzle for 64-elem rows.
// XCD block swizzle; 384 blocks @conc=4.
__global__ __launch_bounds__(256) void pv_kernel(const u16* __restrict__ S,
                                                 const u16* __restrict__ Vt,
                                                 u16* __restrict__ O, int b0) {
    __shared__ u16 lA[128 * 64];
    __shared__ u16 lB[64 * 64];
    int tid = threadIdx.x, wave = tid >> 6, lane = tid & 63;

    int nwg = gridDim.x * gridDim.y;
    int bid = blockIdx.y * gridDim.x + blockIdx.x;
    if ((nwg & 7) == 0) {
        int cpx = nwg >> 3;
        bid = (bid & 7) * cpx + (bid >> 3);
    }
    int zz = bid / gridDim.x, g = zz % Hn, bb = zz / Hn, b = b0 + bb;
    int n0 = (bid % gridDim.x) * 128;

    constexpr size_t RS = (size_t)Hn * Nn;        // S row stride (n -> n+1)
    f32x4 acc[2][4] = {};
    int srow = tid >> 3;
    int sseg = (tid & 7) ^ (srow & 7);
    const u16* gA = S + sidx(bb, n0 + srow, g) + sseg * 8;
    const u16* gB = Vt + ((size_t)(b * Hn + g) * 64 + srow) * Nn + sseg * 8;
    u16* sA = &lA[tid * 8];
    u16* sB = &lB[tid * 8];

    for (int m0 = 0; m0 < Nn; m0 += 64) {
        __syncthreads();
#pragma unroll
        for (int p = 0; p < 4; ++p)
            gload16(gA + m0 + (size_t)(p * 32) * RS, sA + p * 2048);
#pragma unroll
        for (int p = 0; p < 2; ++p)
            gload16(gB + m0 + (size_t)(p * 32) * Nn, sB + p * 2048);
        __syncthreads();

#pragma unroll
        for (int kk = 0; kk < 2; ++kk) {
            int sw = ((kk * 4 + (lane >> 4)) ^ (lane & 7)) * 8;
            short8 bf[4];
#pragma unroll
            for (int c = 0; c < 4; ++c)
                bf[c] = *reinterpret_cast<const short8*>(
                    &lB[(c * 16 + (lane & 15)) * 64 + sw]);
#pragma unroll
            for (int a = 0; a < 2; ++a) {
                short8 af = *reinterpret_cast<const short8*>(
                    &lA[(wave * 32 + a * 16 + (lane & 15)) * 64 + sw]);
#pragma unroll
                for (int c = 0; c < 4; ++c)
                    acc[a][c] = __builtin_amdgcn_mfma_f32_16x16x32_bf16(af, bf[c], acc[a][c], 0, 0, 0);
            }
        }
    }

#pragma unroll
    for (int a = 0; a < 2; ++a) {
        int orow = n0 + wave * 32 + a * 16 + (lane >> 4) * 4;
#pragma unroll
        for (int c = 0; c < 4; ++c) {
            int ocol = g * 64 + c * 16 + (lane & 15);
#pragma unroll
            for (int r = 0; r < 4; ++r)
                O[((size_t)(b * Nn) + orow + r) * Dn + ocol] = f2bf(acc[a][c][r]);
        }
    }
}

// ---------------- launch ----------------
extern "C" void kernel_launch(void* const* d_in, const int* in_sizes, int n_in,
                              void* d_out, int out_size, void* d_ws, size_t ws_size,
                              hipStream_t stream) {
    const float* x    = (const float*)d_in[0];
    const float* wq   = (const float*)d_in[1];
    const float* bq   = (const float*)d_in[2];
    const float* wk   = (const float*)d_in[3];
    const float* bk   = (const float*)d_in[4];
    const float* wv   = (const float*)d_in[5];
    const float* bv   = (const float*)d_in[6];
    const float* wo   = (const float*)d_in[7];
    const float* bo   = (const float*)d_in[8];
    const float* th1w = (const float*)d_in[9];
    const float* th1b = (const float*)d_in[10];
    const float* th2w = (const float*)d_in[11];
    const float* th2b = (const float*)d_in[12];

    size_t off = 0;
    auto alloc = [&](size_t bytes) {
        void* p = (char*)d_ws + off;
        off += (bytes + 255) & ~(size_t)255;
        return p;
    };
    const size_t RD2 = (size_t)Rn * Dn * 2;
    const size_t DD = (size_t)Dn * Dn;
    u16*   xb    = (u16*)alloc(RD2);               // x bf16; reused as PV output O
    u16*   qkvb  = (u16*)alloc((size_t)Rn * LDQ * 2);  // merged [Q|K|V] 8192x2304
    u16*   vtb   = (u16*)alloc(RD2);               // V transposed [b][g][64][1024]
    u16*   wqkvb = (u16*)alloc(3 * DD * 2);        // [wq;wk;wv] contiguous
    u16*   wob   = (u16*)alloc(DD * 2);
    float* bqkv  = (float*)alloc(3 * Dn * 4);      // [bq|bk|bv]

    const size_t SB = (size_t)Hn * Nn * Nn * 2;    // one batch of scores
    size_t base = off;
    int conc = 1;
    if (ws_size > base + SB) {
        size_t c = (ws_size - base) / SB;
        conc = c > 4 ? 4 : (int)c;            // cap 4 (best measured: r11)
    }
    u16* sb = (u16*)((char*)d_ws + base);

    // converts
    cvt4_kernel<<<(Rn * Dn / 4 + 255) / 256, 256, 0, stream>>>(x, xb, Rn * Dn / 4);
    cvtw_kernel<<<dim3((Dn * Dn / 4 + 255) / 256, 4), 256, 0, stream>>>(
        wq, wk, wv, wo, wqkvb, wqkvb + DD, wqkvb + 2 * DD, wob, Dn * Dn / 4);
    bcat_kernel<<<(3 * Dn + 255) / 256, 256, 0, stream>>>(bq, bk, bv, bqkv);

    // merged QKV projection: 8192 x 2304 x 768
    gemm128<true><<<dim3(LDQ / 128, Rn / 128), 256, 0, stream>>>(
        xb, wqkvb, bqkv, qkvb, Rn, LDQ, Dn);

    // V transpose (all batches)
    vtrans_kernel<<<dim3(Nn / 64, Bn * Hn), 256, 0, stream>>>(qkvb, vtb);

    // attention core, conc batches at a time; PV output goes into xb (free now)
    for (int b0 = 0; b0 < Bn; b0 += conc) {
        int g = (Bn - b0) < conc ? (Bn - b0) : conc;
        qk_kernel<<<dim3(Nn / 64, Nn / 64, (Hn / HPB) * g), 256, 0, stream>>>(qkvb, sb, b0);
        mid_kernel<<<g * Nn, 256, 0, stream>>>(sb, th1w, th1b, th2w, th2b);
        pv_kernel<<<dim3(Nn / 128, Hn * g), 256, 0, stream>>>(sb, vtb, xb, b0);
    }

    // final projection -> f32 out
    gemm128<false><<<dim3(Dn / 128, Rn / 128), 256, 0, stream>>>(
        xb, wob, bo, d_out, Rn, Dn, Dn);
}

// Round 17
// 278.392 us; speedup vs baseline: 1.2708x; 1.0048x over previous
//
#include <hip/hip_runtime.h>
#include <hip/hip_bf16.h>

typedef __attribute__((ext_vector_type(8))) short short8;   // bf16x8 (4 VGPR)
typedef __attribute__((ext_vector_type(4))) float f32x4;
typedef __attribute__((ext_vector_type(2))) float f32x2;
typedef __attribute__((ext_vector_type(4))) int i32x4;
typedef __attribute__((ext_vector_type(2))) int i32x2;

typedef unsigned short u16;
typedef unsigned int u32;

#define DEVI static __device__ __forceinline__

constexpr int Bn = 8, Nn = 1024, Dn = 768, Hn = 12;
constexpr int Rn = Bn * Nn;                 // 8192 rows
constexpr int LDQ = 3 * Dn;                 // merged QKV row stride (2304)
constexpr int KOFF = Dn, VOFF = 2 * Dn;     // K/V column offsets in QKV
constexpr float SCALE = 0.125f;             // (768/12)^-0.5 = 1/8
constexpr float LOG2E = 1.44269504088896340736f;
constexpr int HPB = 4;                      // heads per qk block (12 = 3 groups)

// S scratch layout: [bb][n][h][m]  (h-interleaved: one (b,n) row's 12 heads
// are a contiguous 24KB slab -> mid_kernel streams, L2/L3 friendly)
DEVI size_t sidx(int bb, int n, int h) {
    return (((size_t)bb * Nn + n) * Hn + h) * Nn;
}

DEVI u16 f2bf(float f) {
    __hip_bfloat16 h = __float2bfloat16(f);
    return __builtin_bit_cast(u16, h);
}

// RNE bf16 pack of two floats (bit-identical to __float2bfloat16 for finite x)
DEVI u32 bfpack(float a, float b) {
    u32 xa = __builtin_bit_cast(u32, a);
    u32 xb = __builtin_bit_cast(u32, b);
    xa += 0x7fffu + ((xa >> 16) & 1u);
    xb += 0x7fffu + ((xb >> 16) & 1u);
    return (xa >> 16) | (xb & 0xffff0000u);
}

#if __has_builtin(__builtin_amdgcn_exp2f)
#define EXP2(x) __builtin_amdgcn_exp2f(x)
#else
#define EXP2(x) exp2f(x)
#endif
#if __has_builtin(__builtin_amdgcn_rcpf)
#define RCP(x) __builtin_amdgcn_rcpf(x)
#else
#define RCP(x) (1.0f / (x))
#endif

// async global->LDS, 16B per lane; LDS dest must be wave-uniform base + lane*16
DEVI void gload16(const u16* g, u16* l) {
    __builtin_amdgcn_global_load_lds(
        (const __attribute__((address_space(1))) void*)g,
        (__attribute__((address_space(3))) void*)l,
        16, 0, 0);
}

// ---------------- f32 -> bf16 convert, 4 elems/thread ----------------
__global__ __launch_bounds__(256) void cvt4_kernel(const float* __restrict__ in,
                                                   u16* __restrict__ out, int n4) {
    int i = blockIdx.x * 256 + threadIdx.x;
    if (i >= n4) return;
    f32x4 v = *reinterpret_cast<const f32x4*>(&in[(size_t)i * 4]);
    u16 o[4];
#pragma unroll
    for (int j = 0; j < 4; ++j) o[j] = f2bf(v[j]);
    *reinterpret_cast<u32*>(&out[(size_t)i * 4]) = (u32)o[0] | ((u32)o[1] << 16);
    *reinterpret_cast<u32*>(&out[(size_t)i * 4 + 2]) = (u32)o[2] | ((u32)o[3] << 16);
}

// 4 weight matrices + bias concat in one launch; blockIdx.y selects the job
__global__ __launch_bounds__(256) void cvtw_kernel(const float* __restrict__ a,
                                                   const float* __restrict__ b,
                                                   const float* __restrict__ c,
                                                   const float* __restrict__ d,
                                                   u16* oa, u16* ob, u16* oc, u16* od,
                                                   const float* __restrict__ ba,
                                                   const float* __restrict__ bb,
                                                   const float* __restrict__ bc,
                                                   float* __restrict__ bo,
                                                   int n4) {
    int i = blockIdx.x * 256 + threadIdx.x;
    if (blockIdx.y == 4) {                       // bias concat [bq|bk|bv]
        int j = i;
        if (j < Dn) bo[j] = ba[j];
        else if (j < 2 * Dn) bo[j] = bb[j - Dn];
        else if (j < 3 * Dn) bo[j] = bc[j - 2 * Dn];
        return;
    }
    if (i >= n4) return;
    const float* in; u16* out;
    switch (blockIdx.y) {
        case 0: in = a; out = oa; break;
        case 1: in = b; out = ob; break;
        case 2: in = c; out = oc; break;
        default: in = d; out = od; break;
    }
    f32x4 v = *reinterpret_cast<const f32x4*>(&in[(size_t)i * 4]);
    u16 o[4];
#pragma unroll
    for (int j = 0; j < 4; ++j) o[j] = f2bf(v[j]);
    *reinterpret_cast<u32*>(&out[(size_t)i * 4]) = (u32)o[0] | ((u32)o[1] << 16);
    *reinterpret_cast<u32*>(&out[(size_t)i * 4 + 2]) = (u32)o[2] | ((u32)o[3] << 16);
}

// ---------------- 128x128 NT GEMM, BK=64: C = A*B^T + bias ----------------
// 32 MFMA per barrier-round (12 rounds at K=768). Seg-swizzle for 64-elem rows:
// stored seg = (tid&7)^(row&7); read seg = segd^(lane&7). XCD block swizzle.
template <bool BF16OUT>
__global__ __launch_bounds__(256) void gemm128(const u16* __restrict__ A,
                                               const u16* __restrict__ Bm,
                                               const float* __restrict__ bias,
                                               void* __restrict__ Cv,
                                               int M, int Nc, int K) {
    __shared__ u16 lA[128 * 64];
    __shared__ u16 lB[128 * 64];
    int tid = threadIdx.x, wave = tid >> 6, lane = tid & 63;
    int wr = (wave >> 1) * 64, wc = (wave & 1) * 64;

    int nwg = gridDim.x * gridDim.y;
    int bid = blockIdx.y * gridDim.x + blockIdx.x;
    if ((nwg & 7) == 0) {
        int cpx = nwg >> 3;
        bid = (bid & 7) * cpx + (bid >> 3);
    }
    int row0 = (bid / gridDim.x) * 128, col0 = (bid % gridDim.x) * 128;

    f32x4 acc[4][4] = {};

    // staging: pass p covers rows p*32..p*32+31; row = p*32 + (tid>>3), seg = tid&7
    // source seg pre-swizzled: (tid&7) ^ (row&7) == (tid&7) ^ ((tid>>3)&7)
    int srow = tid >> 3;
    int sseg = (tid & 7) ^ (srow & 7);
    const u16* gA = A + (size_t)(row0 + srow) * K + sseg * 8;
    const u16* gB = Bm + (size_t)(col0 + srow) * K + sseg * 8;
    u16* sA = &lA[tid * 8];
    u16* sB = &lB[tid * 8];

    for (int k0 = 0; k0 < K; k0 += 64) {
        __syncthreads();          // prior reads done before overwrite
#pragma unroll
        for (int p = 0; p < 4; ++p) {
            gload16(gA + k0 + (size_t)(p * 32) * K, sA + p * 2048);
            gload16(gB + k0 + (size_t)(p * 32) * K, sB + p * 2048);
        }
        __syncthreads();          // staged data visible

#pragma unroll
        for (int kk = 0; kk < 2; ++kk) {
            int sw = ((kk * 4 + (lane >> 4)) ^ (lane & 7)) * 8;
            short8 af[4], bf[4];
#pragma unroll
            for (int a = 0; a < 4; ++a)
                af[a] = *reinterpret_cast<const short8*>(
                    &lA[(wr + a * 16 + (lane & 15)) * 64 + sw]);
#pragma unroll
            for (int c = 0; c < 4; ++c)
                bf[c] = *reinterpret_cast<const short8*>(
                    &lB[(wc + c * 16 + (lane & 15)) * 64 + sw]);
#pragma unroll
            for (int a = 0; a < 4; ++a)
#pragma unroll
                for (int c = 0; c < 4; ++c)
                    acc[a][c] = __builtin_amdgcn_mfma_f32_16x16x32_bf16(af[a], bf[c], acc[a][c], 0, 0, 0);
        }
    }

#pragma unroll
    for (int a = 0; a < 4; ++a) {
        int crow = row0 + wr + a * 16 + (lane >> 4) * 4;
#pragma unroll
        for (int c = 0; c < 4; ++c) {
            int col = col0 + wc + c * 16 + (lane & 15);
            float bv = bias ? bias[col] : 0.f;
#pragma unroll
            for (int r = 0; r < 4; ++r) {
                float v = acc[a][c][r] + bv;
                if (BF16OUT)
                    reinterpret_cast<u16*>(Cv)[(size_t)(crow + r) * Nc + col] = f2bf(v);
                else
                    reinterpret_cast<float*>(Cv)[(size_t)(crow + r) * Nc + col] = v;
            }
        }
    }
}

// ---------------- batched QK^T, HPB=4 heads per block ----------------
// Stage Q[64n x 256] and K[64m x 256] (4 contiguous head-bands) once -> 64KB LDS,
// compute 4 head-tiles (128 MFMA/block). Row = 256 elems (512B); seg-swizzle
// seg^=(row&7) via pre-swizzled gload source + swizzled read (2-way, free).
__global__ __launch_bounds__(256) void qk_kernel(const u16* __restrict__ QKV,
                                                 u16* __restrict__ S, int b0) {
    __shared__ u16 lQ[64 * 64 * HPB];
    __shared__ u16 lK[64 * 64 * HPB];
    int z = blockIdx.z, hg = z % (Hn / HPB), bb = z / (Hn / HPB), b = b0 + bb;
    int h0 = hg * HPB;
    int n0 = blockIdx.y * 64, m0 = blockIdx.x * 64;
    int tid = threadIdx.x, wave = tid >> 6, lane = tid & 63;

    // stage: chunk c = i*256 + tid; row = c>>5, seg = c&31; source col pre-swizzled
    {
        int seg = tid & 31;
#pragma unroll
        for (int i = 0; i < 8; ++i) {
            int row = i * 8 + (tid >> 5);
            int scol = (seg ^ (row & 7)) * 8;
            const u16* gQ = QKV + ((size_t)(b * Nn) + n0 + row) * LDQ + h0 * 64 + scol;
            const u16* gK = QKV + ((size_t)(b * Nn) + m0 + row) * LDQ + KOFF + h0 * 64 + scol;
            gload16(gQ, &lQ[i * 2048 + tid * 8]);
            gload16(gK, &lK[i * 2048 + tid * 8]);
        }
    }
    __syncthreads();

    f32x4 acc[HPB][4] = {};
#pragma unroll
    for (int hh = 0; hh < HPB; ++hh) {
#pragma unroll
        for (int kk = 0; kk < 2; ++kk) {
            int segd = hh * 8 + kk * 4 + (lane >> 4);      // desired 16B seg in row
            int rK = wave * 16 + (lane & 15);
            short8 bf = *reinterpret_cast<const short8*>(
                &lK[rK * 256 + ((segd ^ (rK & 7)) * 8)]);
#pragma unroll
            for (int a = 0; a < 4; ++a) {
                int rQ = a * 16 + (lane & 15);
                short8 af = *reinterpret_cast<const short8*>(
                    &lQ[rQ * 256 + ((segd ^ (rQ & 7)) * 8)]);
                acc[hh][a] = __builtin_amdgcn_mfma_f32_16x16x32_bf16(af, bf, acc[hh][a], 0, 0, 0);
            }
        }
    }

    int col = m0 + wave * 16 + (lane & 15);
#pragma unroll
    for (int hh = 0; hh < HPB; ++hh)
#pragma unroll
        for (int a = 0; a < 4; ++a) {
            int rowb = n0 + a * 16 + (lane >> 4) * 4;
#pragma unroll
            for (int r = 0; r < 4; ++r)
                S[sidx(bb, rowb + r, h0 + hh) + col] = f2bf(acc[hh][a][r] * SCALE);
        }
}

// ---------------- fused mix1 + softmax + mix2 (in place on S) ----------------
// R8 form (proven best): one block (256 thr) per (bb, n) row; 4 m-positions per
// thread. f32x2 vector math, raw v_exp_f32, v_rcp_f32, manual RNE pack.
// No max-subtraction: |logits| bounded, f32 exp cannot overflow.
__global__ __launch_bounds__(256) void mid_kernel(u16* __restrict__ S,
                                                  const float* __restrict__ w1p,
                                                  const float* __restrict__ b1p,
                                                  const float* __restrict__ w2p,
                                                  const float* __restrict__ b2p) {
    __shared__ float w1[Hn * Hn], w2[Hn * Hn], b1v[Hn], b2v[Hn];
    __shared__ float redS[4][Hn];
    int tid = threadIdx.x;
    for (int i = tid; i < Hn * Hn; i += 256) {
        int g = i % Hn, h = i / Hn;           // store transposed: w[h][g]
        w1[i] = w1p[g * Hn + h] * LOG2E;      // exp2-direct prescale
        w2[i] = w2p[g * Hn + h];
    }
    if (tid < Hn) { b1v[tid] = b1p[tid] * LOG2E; b2v[tid] = b2p[tid]; }
    __syncthreads();

    int bb = blockIdx.x >> 10, n = blockIdx.x & 1023;
    size_t base0 = sidx(bb, n, 0) + tid * 4;      // + h*Nn per head plane

    // prefetch ALL 12 head slabs (12 outstanding dwordx2 loads, one wait)
    i32x2 sv[Hn];
#pragma unroll
    for (int h = 0; h < Hn; ++h)
        sv[h] = *reinterpret_cast<const i32x2*>(&S[base0 + h * Nn]);

    // mix1 (f32x2): acc[g] = b1s[g] + sum_h w1s[g,h] * S[h]   (log2-scaled)
    f32x2 acc[Hn][2];
#pragma unroll
    for (int g = 0; g < Hn; ++g) {
        float b = b1v[g];
        acc[g][0] = f32x2{b, b};
        acc[g][1] = f32x2{b, b};
    }

#pragma unroll
    for (int h = 0; h < Hn; ++h) {
        u32 u0 = (u32)sv[h][0], u1 = (u32)sv[h][1];
        f32x2 v0, v1;
        v0[0] = __builtin_bit_cast(float, u0 << 16);
        v0[1] = __builtin_bit_cast(float, u0 & 0xffff0000u);
        v1[0] = __builtin_bit_cast(float, u1 << 16);
        v1[1] = __builtin_bit_cast(float, u1 & 0xffff0000u);
#pragma unroll
        for (int g = 0; g < Hn; ++g) {
            float w = w1[h * Hn + g];
            f32x2 wv = {w, w};
            acc[g][0] += wv * v0;
            acc[g][1] += wv * v1;
        }
    }

    // exp2 + row-sum
    float sm[Hn];
#pragma unroll
    for (int g = 0; g < Hn; ++g) {
        acc[g][0][0] = EXP2(acc[g][0][0]);
        acc[g][0][1] = EXP2(acc[g][0][1]);
        acc[g][1][0] = EXP2(acc[g][1][0]);
        acc[g][1][1] = EXP2(acc[g][1][1]);
        f32x2 s2 = acc[g][0] + acc[g][1];
        sm[g] = s2[0] + s2[1];
    }
#pragma unroll
    for (int off = 32; off; off >>= 1)
#pragma unroll
        for (int g = 0; g < Hn; ++g) sm[g] += __shfl_xor(sm[g], off, 64);
    int wv2 = tid >> 6, ln = tid & 63;
    if (ln < Hn) redS[wv2][ln] = sm[ln];
    __syncthreads();
#pragma unroll
    for (int g = 0; g < Hn; ++g) {
        float inv = RCP(redS[0][g] + redS[1][g] + redS[2][g] + redS[3][g]);
        f32x2 iv = {inv, inv};
        acc[g][0] *= iv;
        acc[g][1] *= iv;
    }

    // mix2 (f32x2) + RNE-packed store: out[g] = b2[g] + sum_h w2[g,h] * P[h]
#pragma unroll
    for (int g = 0; g < Hn; ++g) {
        float b = b2v[g];
        f32x2 o0 = {b, b}, o1 = {b, b};
#pragma unroll
        for (int h = 0; h < Hn; ++h) {
            float w = w2[h * Hn + g];
            f32x2 wv = {w, w};
            o0 += wv * acc[h][0];
            o1 += wv * acc[h][1];
        }
        i32x2 ob;
        ob[0] = (int)bfpack(o0[0], o0[1]);
        ob[1] = (int)bfpack(o1[0], o1[1]);
        *reinterpret_cast<i32x2*>(&S[base0 + g * Nn]) = ob;
    }
}

// ---------------- V transpose: Vt[b][g][d=64][m=1024] = QKV[b*Nn+m][VOFF+g*64+d] ----------------
__global__ __launch_bounds__(256) void vtrans_kernel(const u16* __restrict__ QKV,
                                                     u16* __restrict__ Vt) {
    __shared__ u16 lT[64 * 64];
    int bg = blockIdx.y, g = bg % Hn, b = bg / Hn;
    int m0 = blockIdx.x * 64;
    int tid = threadIdx.x;

    int r = tid >> 3, d8 = tid & 7;
#pragma unroll
    for (int p = 0; p < 2; ++p) {
        int rr = r + p * 32;
        i32x4 v = *reinterpret_cast<const i32x4*>(
            &QKV[((size_t)(b * Nn) + m0 + rr) * LDQ + VOFF + g * 64 + d8 * 8]);
        *reinterpret_cast<i32x4*>(&lT[rr * 64 + ((d8 ^ (rr & 7)) * 8)]) = v;
    }
    __syncthreads();

    int d = tid >> 3, rs = (tid & 7) * 8;
#pragma unroll
    for (int p = 0; p < 2; ++p) {
        int dd = d + p * 32;
        u16 o[8];
#pragma unroll
        for (int j = 0; j < 8; ++j)
            o[j] = lT[(rs + j) * 64 + (((dd >> 3) ^ j) * 8) + (dd & 7)];
        *reinterpret_cast<i32x4*>(&Vt[((size_t)(b * Hn + g) * 64 + dd) * Nn + m0 + rs]) =
            *reinterpret_cast<const i32x4*>(o);
    }
}

// ---------------- PV as NT GEMM: tile 128n x 64d, BK=64 over m ----------------
// 16 MFMA per barrier-round (16 rounds). Seg-swizzle for 64-elem rows.
// XCD block swizzle.
__global__ __launch_bounds__(256) void pv_kernel(const u16* __restrict__ S,
                                                 const u16* __restrict__ Vt,
                                                 u16* __restrict__ O, int b0) {
    __shared__ u16 lA[128 * 64];
    __shared__ u16 lB[64 * 64];
    int tid = threadIdx.x, wave = tid >> 6, lane = tid & 63;

    int nwg = gridDim.x * gridDim.y;
    int bid = blockIdx.y * gridDim.x + blockIdx.x;
    if ((nwg & 7) == 0) {
        int cpx = nwg >> 3;
        bid = (bid & 7) * cpx + (bid >> 3);
    }
    int zz = bid / gridDim.x, g = zz % Hn, bb = zz / Hn, b = b0 + bb;
    int n0 = (bid % gridDim.x) * 128;

    constexpr size_t RS = (size_t)Hn * Nn;        // S row stride (n -> n+1)
    f32x4 acc[2][4] = {};
    int srow = tid >> 3;
    int sseg = (tid & 7) ^ (srow & 7);
    const u16* gA = S + sidx(bb, n0 + srow, g) + sseg * 8;
    const u16* gB = Vt + ((size_t)(b * Hn + g) * 64 + srow) * Nn + sseg * 8;
    u16* sA = &lA[tid * 8];
    u16* sB = &lB[tid * 8];

    for (int m0 = 0; m0 < Nn; m0 += 64) {
        __syncthreads();
#pragma unroll
        for (int p = 0; p < 4; ++p)
            gload16(gA + m0 + (size_t)(p * 32) * RS, sA + p * 2048);
#pragma unroll
        for (int p = 0; p < 2; ++p)
            gload16(gB + m0 + (size_t)(p * 32) * Nn, sB + p * 2048);
        __syncthreads();

#pragma unroll
        for (int kk = 0; kk < 2; ++kk) {
            int sw = ((kk * 4 + (lane >> 4)) ^ (lane & 7)) * 8;
            short8 bf[4];
#pragma unroll
            for (int c = 0; c < 4; ++c)
                bf[c] = *reinterpret_cast<const short8*>(
                    &lB[(c * 16 + (lane & 15)) * 64 + sw]);
#pragma unroll
            for (int a = 0; a < 2; ++a) {
                short8 af = *reinterpret_cast<const short8*>(
                    &lA[(wave * 32 + a * 16 + (lane & 15)) * 64 + sw]);
#pragma unroll
                for (int c = 0; c < 4; ++c)
                    acc[a][c] = __builtin_amdgcn_mfma_f32_16x16x32_bf16(af, bf[c], acc[a][c], 0, 0, 0);
            }
        }
    }

#pragma unroll
    for (int a = 0; a < 2; ++a) {
        int orow = n0 + wave * 32 + a * 16 + (lane >> 4) * 4;
#pragma unroll
        for (int c = 0; c < 4; ++c) {
            int ocol = g * 64 + c * 16 + (lane & 15);
#pragma unroll
            for (int r = 0; r < 4; ++r)
                O[((size_t)(b * Nn) + orow + r) * Dn + ocol] = f2bf(acc[a][c][r]);
        }
    }
}

// ---------------- launch ----------------
extern "C" void kernel_launch(void* const* d_in, const int* in_sizes, int n_in,
                              void* d_out, int out_size, void* d_ws, size_t ws_size,
                              hipStream_t stream) {
    const float* x    = (const float*)d_in[0];
    const float* wq   = (const float*)d_in[1];
    const float* bq   = (const float*)d_in[2];
    const float* wk   = (const float*)d_in[3];
    const float* bk   = (const float*)d_in[4];
    const float* wv   = (const float*)d_in[5];
    const float* bv   = (const float*)d_in[6];
    const float* wo   = (const float*)d_in[7];
    const float* bo   = (const float*)d_in[8];
    const float* th1w = (const float*)d_in[9];
    const float* th1b = (const float*)d_in[10];
    const float* th2w = (const float*)d_in[11];
    const float* th2b = (const float*)d_in[12];

    size_t off = 0;
    auto alloc = [&](size_t bytes) {
        void* p = (char*)d_ws + off;
        off += (bytes + 255) & ~(size_t)255;
        return p;
    };
    const size_t RD2 = (size_t)Rn * Dn * 2;
    const size_t DD = (size_t)Dn * Dn;
    u16*   xb    = (u16*)alloc(RD2);               // x bf16; reused as PV output O
    u16*   qkvb  = (u16*)alloc((size_t)Rn * LDQ * 2);  // merged [Q|K|V] 8192x2304
    u16*   vtb   = (u16*)alloc(RD2);               // V transposed [b][g][64][1024]
    u16*   wqkvb = (u16*)alloc(3 * DD * 2);        // [wq;wk;wv] contiguous
    u16*   wob   = (u16*)alloc(DD * 2);
    float* bqkv  = (float*)alloc(3 * Dn * 4);      // [bq|bk|bv]

    const size_t SB = (size_t)Hn * Nn * Nn * 2;    // one batch of scores
    size_t base = off;
    int conc = 1;
    if (ws_size > base + SB) {
        size_t c = (ws_size - base) / SB;
        conc = c > 8 ? 8 : (int)c;            // prefer 8 (single group, fewest launches)
    }
    if (conc > 4 && conc < 8) conc = 4;       // keep groups uniform (8 or 4 or fewer)
    if (conc == 3) conc = 2;
    u16* sb = (u16*)((char*)d_ws + base);

    // converts (weights + biases in one launch)
    cvt4_kernel<<<(Rn * Dn / 4 + 255) / 256, 256, 0, stream>>>(x, xb, Rn * Dn / 4);
    cvtw_kernel<<<dim3((Dn * Dn / 4 + 255) / 256, 5), 256, 0, stream>>>(
        wq, wk, wv, wo, wqkvb, wqkvb + DD, wqkvb + 2 * DD, wob,
        bq, bk, bv, bqkv, Dn * Dn / 4);

    // merged QKV projection: 8192 x 2304 x 768
    gemm128<true><<<dim3(LDQ / 128, Rn / 128), 256, 0, stream>>>(
        xb, wqkvb, bqkv, qkvb, Rn, LDQ, Dn);

    // V transpose (all batches)
    vtrans_kernel<<<dim3(Nn / 64, Bn * Hn), 256, 0, stream>>>(qkvb, vtb);

    // attention core, conc batches at a time; PV output goes into xb (free now)
    for (int b0 = 0; b0 < Bn; b0 += conc) {
        int g = (Bn - b0) < conc ? (Bn - b0) : conc;
        qk_kernel<<<dim3(Nn / 64, Nn / 64, (Hn / HPB) * g), 256, 0, stream>>>(qkvb, sb, b0);
        mid_kernel<<<g * Nn, 256, 0, stream>>>(sb, th1w, th1b, th2w, th2b);
        pv_kernel<<<dim3(Nn / 128, Hn * g), 256, 0, stream>>>(sb, vtb, xb, b0);
    }

    // final projection -> f32 out
    gemm128<false><<<dim3(Dn / 128, Rn / 128), 256, 0, stream>>>(
        xb, wob, bo, d_out, Rn, Dn, Dn);
}

// Round 18
// 268.010 us; speedup vs baseline: 1.3200x; 1.0387x over previous
//
#include <hip/hip_runtime.h>
#include <hip/hip_bf16.h>

typedef __attribute__((ext_vector_type(8))) short short8;   // bf16x8 (4 VGPR)
typedef __attribute__((ext_vector_type(4))) float f32x4;
typedef __attribute__((ext_vector_type(2))) float f32x2;
typedef __attribute__((ext_vector_type(4))) int i32x4;
typedef __attribute__((ext_vector_type(2))) int i32x2;

typedef unsigned short u16;
typedef unsigned int u32;

#define DEVI static __device__ __forceinline__

constexpr int Bn = 8, Nn = 1024, Dn = 768, Hn = 12;
constexpr int Rn = Bn * Nn;                 // 8192 rows
constexpr int LDQ = 3 * Dn;                 // merged QKV row stride (2304)
constexpr int KOFF = Dn, VOFF = 2 * Dn;     // K/V column offsets in QKV
constexpr float SCALE = 0.125f;             // (768/12)^-0.5 = 1/8
constexpr float LOG2E = 1.44269504088896340736f;
constexpr int HPB = 4;                      // heads per qk block (12 = 3 groups)

// S scratch layout: [bb][n][h][m]  (h-interleaved: one (b,n) row's 12 heads
// are a contiguous 24KB slab -> mid_kernel streams, L2/L3 friendly)
DEVI size_t sidx(int bb, int n, int h) {
    return (((size_t)bb * Nn + n) * Hn + h) * Nn;
}

DEVI u16 f2bf(float f) {
    __hip_bfloat16 h = __float2bfloat16(f);
    return __builtin_bit_cast(u16, h);
}

// RNE bf16 pack of two floats (bit-identical to __float2bfloat16 for finite x)
DEVI u32 bfpack(float a, float b) {
    u32 xa = __builtin_bit_cast(u32, a);
    u32 xb = __builtin_bit_cast(u32, b);
    xa += 0x7fffu + ((xa >> 16) & 1u);
    xb += 0x7fffu + ((xb >> 16) & 1u);
    return (xa >> 16) | (xb & 0xffff0000u);
}

#if __has_builtin(__builtin_amdgcn_exp2f)
#define EXP2(x) __builtin_amdgcn_exp2f(x)
#else
#define EXP2(x) exp2f(x)
#endif
#if __has_builtin(__builtin_amdgcn_rcpf)
#define RCP(x) __builtin_amdgcn_rcpf(x)
#else
#define RCP(x) (1.0f / (x))
#endif

// async global->LDS, 16B per lane; LDS dest must be wave-uniform base + lane*16
DEVI void gload16(const u16* g, u16* l) {
    __builtin_amdgcn_global_load_lds(
        (const __attribute__((address_space(1))) void*)g,
        (__attribute__((address_space(3))) void*)l,
        16, 0, 0);
}

// ---------------- f32 -> bf16 convert, 4 elems/thread ----------------
__global__ __launch_bounds__(256) void cvt4_kernel(const float* __restrict__ in,
                                                   u16* __restrict__ out, int n4) {
    int i = blockIdx.x * 256 + threadIdx.x;
    if (i >= n4) return;
    f32x4 v = *reinterpret_cast<const f32x4*>(&in[(size_t)i * 4]);
    u16 o[4];
#pragma unroll
    for (int j = 0; j < 4; ++j) o[j] = f2bf(v[j]);
    *reinterpret_cast<u32*>(&out[(size_t)i * 4]) = (u32)o[0] | ((u32)o[1] << 16);
    *reinterpret_cast<u32*>(&out[(size_t)i * 4 + 2]) = (u32)o[2] | ((u32)o[3] << 16);
}

// 4 weight matrices + bias concat in one launch; blockIdx.y selects the job
__global__ __launch_bounds__(256) void cvtw_kernel(const float* __restrict__ a,
                                                   const float* __restrict__ b,
                                                   const float* __restrict__ c,
                                                   const float* __restrict__ d,
                                                   u16* oa, u16* ob, u16* oc, u16* od,
                                                   const float* __restrict__ ba,
                                                   const float* __restrict__ bb,
                                                   const float* __restrict__ bc,
                                                   float* __restrict__ bo,
                                                   int n4) {
    int i = blockIdx.x * 256 + threadIdx.x;
    if (blockIdx.y == 4) {                       // bias concat [bq|bk|bv]
        int j = i;
        if (j < Dn) bo[j] = ba[j];
        else if (j < 2 * Dn) bo[j] = bb[j - Dn];
        else if (j < 3 * Dn) bo[j] = bc[j - 2 * Dn];
        return;
    }
    if (i >= n4) return;
    const float* in; u16* out;
    switch (blockIdx.y) {
        case 0: in = a; out = oa; break;
        case 1: in = b; out = ob; break;
        case 2: in = c; out = oc; break;
        default: in = d; out = od; break;
    }
    f32x4 v = *reinterpret_cast<const f32x4*>(&in[(size_t)i * 4]);
    u16 o[4];
#pragma unroll
    for (int j = 0; j < 4; ++j) o[j] = f2bf(v[j]);
    *reinterpret_cast<u32*>(&out[(size_t)i * 4]) = (u32)o[0] | ((u32)o[1] << 16);
    *reinterpret_cast<u32*>(&out[(size_t)i * 4 + 2]) = (u32)o[2] | ((u32)o[3] << 16);
}

// ---------------- 128x128 NT GEMM, BK=64: C = A*B^T + bias ----------------
// 32 MFMA per barrier-round (12 rounds at K=768). Seg-swizzle for 64-elem rows:
// stored seg = (tid&7)^(row&7); read seg = segd^(lane&7). XCD block swizzle.
template <bool BF16OUT>
__global__ __launch_bounds__(256) void gemm128(const u16* __restrict__ A,
                                               const u16* __restrict__ Bm,
                                               const float* __restrict__ bias,
                                               void* __restrict__ Cv,
                                               int M, int Nc, int K) {
    __shared__ u16 lA[128 * 64];
    __shared__ u16 lB[128 * 64];
    int tid = threadIdx.x, wave = tid >> 6, lane = tid & 63;
    int wr = (wave >> 1) * 64, wc = (wave & 1) * 64;

    int nwg = gridDim.x * gridDim.y;
    int bid = blockIdx.y * gridDim.x + blockIdx.x;
    if ((nwg & 7) == 0) {
        int cpx = nwg >> 3;
        bid = (bid & 7) * cpx + (bid >> 3);
    }
    int row0 = (bid / gridDim.x) * 128, col0 = (bid % gridDim.x) * 128;

    f32x4 acc[4][4] = {};

    // staging: pass p covers rows p*32..p*32+31; row = p*32 + (tid>>3), seg = tid&7
    // source seg pre-swizzled: (tid&7) ^ (row&7) == (tid&7) ^ ((tid>>3)&7)
    int srow = tid >> 3;
    int sseg = (tid & 7) ^ (srow & 7);
    const u16* gA = A + (size_t)(row0 + srow) * K + sseg * 8;
    const u16* gB = Bm + (size_t)(col0 + srow) * K + sseg * 8;
    u16* sA = &lA[tid * 8];
    u16* sB = &lB[tid * 8];

    for (int k0 = 0; k0 < K; k0 += 64) {
        __syncthreads();          // prior reads done before overwrite
#pragma unroll
        for (int p = 0; p < 4; ++p) {
            gload16(gA + k0 + (size_t)(p * 32) * K, sA + p * 2048);
            gload16(gB + k0 + (size_t)(p * 32) * K, sB + p * 2048);
        }
        __syncthreads();          // staged data visible

#pragma unroll
        for (int kk = 0; kk < 2; ++kk) {
            int sw = ((kk * 4 + (lane >> 4)) ^ (lane & 7)) * 8;
            short8 af[4], bf[4];
#pragma unroll
            for (int a = 0; a < 4; ++a)
                af[a] = *reinterpret_cast<const short8*>(
                    &lA[(wr + a * 16 + (lane & 15)) * 64 + sw]);
#pragma unroll
            for (int c = 0; c < 4; ++c)
                bf[c] = *reinterpret_cast<const short8*>(
                    &lB[(wc + c * 16 + (lane & 15)) * 64 + sw]);
#pragma unroll
            for (int a = 0; a < 4; ++a)
#pragma unroll
                for (int c = 0; c < 4; ++c)
                    acc[a][c] = __builtin_amdgcn_mfma_f32_16x16x32_bf16(af[a], bf[c], acc[a][c], 0, 0, 0);
        }
    }

#pragma unroll
    for (int a = 0; a < 4; ++a) {
        int crow = row0 + wr + a * 16 + (lane >> 4) * 4;
#pragma unroll
        for (int c = 0; c < 4; ++c) {
            int col = col0 + wc + c * 16 + (lane & 15);
            float bv = bias ? bias[col] : 0.f;
#pragma unroll
            for (int r = 0; r < 4; ++r) {
                float v = acc[a][c][r] + bv;
                if (BF16OUT)
                    reinterpret_cast<u16*>(Cv)[(size_t)(crow + r) * Nc + col] = f2bf(v);
                else
                    reinterpret_cast<float*>(Cv)[(size_t)(crow + r) * Nc + col] = v;
            }
        }
    }
}

// ---------------- batched QK^T, HPB=4 heads per block ----------------
// Stage Q[64n x 256] and K[64m x 256] (4 contiguous head-bands) once -> 64KB LDS,
// compute 4 head-tiles (128 MFMA/block). Row = 256 elems (512B); seg-swizzle
// seg^=(row&7) via pre-swizzled gload source + swizzled read (2-way, free).
__global__ __launch_bounds__(256) void qk_kernel(const u16* __restrict__ QKV,
                                                 u16* __restrict__ S, int b0) {
    __shared__ u16 lQ[64 * 64 * HPB];
    __shared__ u16 lK[64 * 64 * HPB];
    int z = blockIdx.z, hg = z % (Hn / HPB), bb = z / (Hn / HPB), b = b0 + bb;
    int h0 = hg * HPB;
    int n0 = blockIdx.y * 64, m0 = blockIdx.x * 64;
    int tid = threadIdx.x, wave = tid >> 6, lane = tid & 63;

    // stage: chunk c = i*256 + tid; row = c>>5, seg = c&31; source col pre-swizzled
    {
        int seg = tid & 31;
#pragma unroll
        for (int i = 0; i < 8; ++i) {
            int row = i * 8 + (tid >> 5);
            int scol = (seg ^ (row & 7)) * 8;
            const u16* gQ = QKV + ((size_t)(b * Nn) + n0 + row) * LDQ + h0 * 64 + scol;
            const u16* gK = QKV + ((size_t)(b * Nn) + m0 + row) * LDQ + KOFF + h0 * 64 + scol;
            gload16(gQ, &lQ[i * 2048 + tid * 8]);
            gload16(gK, &lK[i * 2048 + tid * 8]);
        }
    }
    __syncthreads();

    f32x4 acc[HPB][4] = {};
#pragma unroll
    for (int hh = 0; hh < HPB; ++hh) {
#pragma unroll
        for (int kk = 0; kk < 2; ++kk) {
            int segd = hh * 8 + kk * 4 + (lane >> 4);      // desired 16B seg in row
            int rK = wave * 16 + (lane & 15);
            short8 bf = *reinterpret_cast<const short8*>(
                &lK[rK * 256 + ((segd ^ (rK & 7)) * 8)]);
#pragma unroll
            for (int a = 0; a < 4; ++a) {
                int rQ = a * 16 + (lane & 15);
                short8 af = *reinterpret_cast<const short8*>(
                    &lQ[rQ * 256 + ((segd ^ (rQ & 7)) * 8)]);
                acc[hh][a] = __builtin_amdgcn_mfma_f32_16x16x32_bf16(af, bf, acc[hh][a], 0, 0, 0);
            }
        }
    }

    int col = m0 + wave * 16 + (lane & 15);
#pragma unroll
    for (int hh = 0; hh < HPB; ++hh)
#pragma unroll
        for (int a = 0; a < 4; ++a) {
            int rowb = n0 + a * 16 + (lane >> 4) * 4;
#pragma unroll
            for (int r = 0; r < 4; ++r)
                S[sidx(bb, rowb + r, h0 + hh) + col] = f2bf(acc[hh][a][r] * SCALE);
        }
}

// ---------------- fused mix1 + softmax + mix2 (in place on S) ----------------
// One block (256 thr) per (bb, n) row; 4 m-positions per thread.
// R18: th-weights read DIRECTLY from global with uniform compile-time indices
// -> hipcc scalarizes to s_load (scalar pipe, hoisted; v_pk_fma takes the SGPR
// operand). Removes 288 ds_read_b32 issue slots + the staging barrier per block.
// LOG2E folded into the unpacked S values (24 pk_mul) instead of the weights.
// No max-subtraction: |logits| bounded, f32 exp cannot overflow.
__global__ __launch_bounds__(256) void mid_kernel(u16* __restrict__ S,
                                                  const float* __restrict__ w1p,
                                                  const float* __restrict__ b1p,
                                                  const float* __restrict__ w2p,
                                                  const float* __restrict__ b2p) {
    __shared__ float redS[4][Hn];
    int tid = threadIdx.x;

    int bb = blockIdx.x >> 10, n = blockIdx.x & 1023;
    size_t base0 = sidx(bb, n, 0) + tid * 4;      // + h*Nn per head plane

    // prefetch ALL 12 head slabs (12 outstanding dwordx2 loads, one wait)
    i32x2 sv[Hn];
#pragma unroll
    for (int h = 0; h < Hn; ++h)
        sv[h] = *reinterpret_cast<const i32x2*>(&S[base0 + h * Nn]);

    // mix1 (f32x2): acc[g] = b1[g]*L2E + sum_h w1[g,h] * (S[h]*L2E)
    const f32x2 L2 = {LOG2E, LOG2E};
    f32x2 acc[Hn][2];
#pragma unroll
    for (int g = 0; g < Hn; ++g) {
        float b = b1p[g] * LOG2E;                 // uniform -> s_load + 1 v_mul
        acc[g][0] = f32x2{b, b};
        acc[g][1] = f32x2{b, b};
    }

#pragma unroll
    for (int h = 0; h < Hn; ++h) {
        u32 u0 = (u32)sv[h][0], u1 = (u32)sv[h][1];
        f32x2 v0, v1;
        v0[0] = __builtin_bit_cast(float, u0 << 16);
        v0[1] = __builtin_bit_cast(float, u0 & 0xffff0000u);
        v1[0] = __builtin_bit_cast(float, u1 << 16);
        v1[1] = __builtin_bit_cast(float, u1 & 0xffff0000u);
        v0 *= L2;
        v1 *= L2;
#pragma unroll
        for (int g = 0; g < Hn; ++g) {
            float w = w1p[g * Hn + h];            // uniform idx -> SGPR
            f32x2 wv = {w, w};
            acc[g][0] += wv * v0;
            acc[g][1] += wv * v1;
        }
    }

    // exp2 + row-sum
    float sm[Hn];
#pragma unroll
    for (int g = 0; g < Hn; ++g) {
        acc[g][0][0] = EXP2(acc[g][0][0]);
        acc[g][0][1] = EXP2(acc[g][0][1]);
        acc[g][1][0] = EXP2(acc[g][1][0]);
        acc[g][1][1] = EXP2(acc[g][1][1]);
        f32x2 s2 = acc[g][0] + acc[g][1];
        sm[g] = s2[0] + s2[1];
    }
#pragma unroll
    for (int off = 32; off; off >>= 1)
#pragma unroll
        for (int g = 0; g < Hn; ++g) sm[g] += __shfl_xor(sm[g], off, 64);
    int wv2 = tid >> 6, ln = tid & 63;
    if (ln < Hn) redS[wv2][ln] = sm[ln];
    __syncthreads();
#pragma unroll
    for (int g = 0; g < Hn; ++g) {
        float inv = RCP(redS[0][g] + redS[1][g] + redS[2][g] + redS[3][g]);
        f32x2 iv = {inv, inv};
        acc[g][0] *= iv;
        acc[g][1] *= iv;
    }

    // mix2 (f32x2) + RNE-packed store: out[g] = b2[g] + sum_h w2[g,h] * P[h]
#pragma unroll
    for (int g = 0; g < Hn; ++g) {
        float b = b2p[g];                         // uniform -> s_load
        f32x2 o0 = {b, b}, o1 = {b, b};
#pragma unroll
        for (int h = 0; h < Hn; ++h) {
            float w = w2p[g * Hn + h];            // uniform idx -> SGPR
            f32x2 wv = {w, w};
            o0 += wv * acc[h][0];
            o1 += wv * acc[h][1];
        }
        i32x2 ob;
        ob[0] = (int)bfpack(o0[0], o0[1]);
        ob[1] = (int)bfpack(o1[0], o1[1]);
        *reinterpret_cast<i32x2*>(&S[base0 + g * Nn]) = ob;
    }
}

// ---------------- V transpose: Vt[b][g][d=64][m=1024] = QKV[b*Nn+m][VOFF+g*64+d] ----------------
__global__ __launch_bounds__(256) void vtrans_kernel(const u16* __restrict__ QKV,
                                                     u16* __restrict__ Vt) {
    __shared__ u16 lT[64 * 64];
    int bg = blockIdx.y, g = bg % Hn, b = bg / Hn;
    int m0 = blockIdx.x * 64;
    int tid = threadIdx.x;

    int r = tid >> 3, d8 = tid & 7;
#pragma unroll
    for (int p = 0; p < 2; ++p) {
        int rr = r + p * 32;
        i32x4 v = *reinterpret_cast<const i32x4*>(
            &QKV[((size_t)(b * Nn) + m0 + rr) * LDQ + VOFF + g * 64 + d8 * 8]);
        *reinterpret_cast<i32x4*>(&lT[rr * 64 + ((d8 ^ (rr & 7)) * 8)]) = v;
    }
    __syncthreads();

    int d = tid >> 3, rs = (tid & 7) * 8;
#pragma unroll
    for (int p = 0; p < 2; ++p) {
        int dd = d + p * 32;
        u16 o[8];
#pragma unroll
        for (int j = 0; j < 8; ++j)
            o[j] = lT[(rs + j) * 64 + (((dd >> 3) ^ j) * 8) + (dd & 7)];
        *reinterpret_cast<i32x4*>(&Vt[((size_t)(b * Hn + g) * 64 + dd) * Nn + m0 + rs]) =
            *reinterpret_cast<const i32x4*>(o);
    }
}

// ---------------- PV as NT GEMM: tile 128n x 64d, BK=64 over m ----------------
// 16 MFMA per barrier-round (16 rounds). Seg-swizzle for 64-elem rows.
// XCD block swizzle.
__global__ __launch_bounds__(256) void pv_kernel(const u16* __restrict__ S,
                                                 const u16* __restrict__ Vt,
                                                 u16* __restrict__ O, int b0) {
    __shared__ u16 lA[128 * 64];
    __shared__ u16 lB[64 * 64];
    int tid = threadIdx.x, wave = tid >> 6, lane = tid & 63;

    int nwg = gridDim.x * gridDim.y;
    int bid = blockIdx.y * gridDim.x + blockIdx.x;
    if ((nwg & 7) == 0) {
        int cpx = nwg >> 3;
        bid = (bid & 7) * cpx + (bid >> 3);
    }
    int zz = bid / gridDim.x, g = zz % Hn, bb = zz / Hn, b = b0 + bb;
    int n0 = (bid % gridDim.x) * 128;

    constexpr size_t RS = (size_t)Hn * Nn;        // S row stride (n -> n+1)
    f32x4 acc[2][4] = {};
    int srow = tid >> 3;
    int sseg = (tid & 7) ^ (srow & 7);
    const u16* gA = S + sidx(bb, n0 + srow, g) + sseg * 8;
    const u16* gB = Vt + ((size_t)(b * Hn + g) * 64 + srow) * Nn + sseg * 8;
    u16* sA = &lA[tid * 8];
    u16* sB = &lB[tid * 8];

    for (int m0 = 0; m0 < Nn; m0 += 64) {
        __syncthreads();
#pragma unroll
        for (int p = 0; p < 4; ++p)
            gload16(gA + m0 + (size_t)(p * 32) * RS, sA + p * 2048);
#pragma unroll
        for (int p = 0; p < 2; ++p)
            gload16(gB + m0 + (size_t)(p * 32) * Nn, sB + p * 2048);
        __syncthreads();

#pragma unroll
        for (int kk = 0; kk < 2; ++kk) {
            int sw = ((kk * 4 + (lane >> 4)) ^ (lane & 7)) * 8;
            short8 bf[4];
#pragma unroll
            for (int c = 0; c < 4; ++c)
                bf[c] = *reinterpret_cast<const short8*>(
                    &lB[(c * 16 + (lane & 15)) * 64 + sw]);
#pragma unroll
            for (int a = 0; a < 2; ++a) {
                short8 af = *reinterpret_cast<const short8*>(
                    &lA[(wave * 32 + a * 16 + (lane & 15)) * 64 + sw]);
#pragma unroll
                for (int c = 0; c < 4; ++c)
                    acc[a][c] = __builtin_amdgcn_mfma_f32_16x16x32_bf16(af, bf[c], acc[a][c], 0, 0, 0);
            }
        }
    }

#pragma unroll
    for (int a = 0; a < 2; ++a) {
        int orow = n0 + wave * 32 + a * 16 + (lane >> 4) * 4;
#pragma unroll
        for (int c = 0; c < 4; ++c) {
            int ocol = g * 64 + c * 16 + (lane & 15);
#pragma unroll
            for (int r = 0; r < 4; ++r)
                O[((size_t)(b * Nn) + orow + r) * Dn + ocol] = f2bf(acc[a][c][r]);
        }
    }
}

// ---------------- launch ----------------
extern "C" void kernel_launch(void* const* d_in, const int* in_sizes, int n_in,
                              void* d_out, int out_size, void* d_ws, size_t ws_size,
                              hipStream_t stream) {
    const float* x    = (const float*)d_in[0];
    const float* wq   = (const float*)d_in[1];
    const float* bq   = (const float*)d_in[2];
    const float* wk   = (const float*)d_in[3];
    const float* bk   = (const float*)d_in[4];
    const float* wv   = (const float*)d_in[5];
    const float* bv   = (const float*)d_in[6];
    const float* wo   = (const float*)d_in[7];
    const float* bo   = (const float*)d_in[8];
    const float* th1w = (const float*)d_in[9];
    const float* th1b = (const float*)d_in[10];
    const float* th2w = (const float*)d_in[11];
    const float* th2b = (const float*)d_in[12];

    size_t off = 0;
    auto alloc = [&](size_t bytes) {
        void* p = (char*)d_ws + off;
        off += (bytes + 255) & ~(size_t)255;
        return p;
    };
    const size_t RD2 = (size_t)Rn * Dn * 2;
    const size_t DD = (size_t)Dn * Dn;
    u16*   xb    = (u16*)alloc(RD2);               // x bf16; reused as PV output O
    u16*   qkvb  = (u16*)alloc((size_t)Rn * LDQ * 2);  // merged [Q|K|V] 8192x2304
    u16*   vtb   = (u16*)alloc(RD2);               // V transposed [b][g][64][1024]
    u16*   wqkvb = (u16*)alloc(3 * DD * 2);        // [wq;wk;wv] contiguous
    u16*   wob   = (u16*)alloc(DD * 2);
    float* bqkv  = (float*)alloc(3 * Dn * 4);      // [bq|bk|bv]

    const size_t SB = (size_t)Hn * Nn * Nn * 2;    // one batch of scores
    size_t base = off;
    int conc = 1;
    if (ws_size > base + SB) {
        size_t c = (ws_size - base) / SB;
        conc = c > 8 ? 8 : (int)c;            // prefer 8 (single group, fewest launches)
    }
    if (conc > 4 && conc < 8) conc = 4;       // keep groups uniform (8 or 4 or fewer)
    if (conc == 3) conc = 2;
    u16* sb = (u16*)((char*)d_ws + base);

    // converts (weights + biases in one launch)
    cvt4_kernel<<<(Rn * Dn / 4 + 255) / 256, 256, 0, stream>>>(x, xb, Rn * Dn / 4);
    cvtw_kernel<<<dim3((Dn * Dn / 4 + 255) / 256, 5), 256, 0, stream>>>(
        wq, wk, wv, wo, wqkvb, wqkvb + DD, wqkvb + 2 * DD, wob,
        bq, bk, bv, bqkv, Dn * Dn / 4);

    // merged QKV projection: 8192 x 2304 x 768
    gemm128<true><<<dim3(LDQ / 128, Rn / 128), 256, 0, stream>>>(
        xb, wqkvb, bqkv, qkvb, Rn, LDQ, Dn);

    // V transpose (all batches)
    vtrans_kernel<<<dim3(Nn / 64, Bn * Hn), 256, 0, stream>>>(qkvb, vtb);

    // attention core, conc batches at a time; PV output goes into xb (free now)
    for (int b0 = 0; b0 < Bn; b0 += conc) {
        int g = (Bn - b0) < conc ? (Bn - b0) : conc;
        qk_kernel<<<dim3(Nn / 64, Nn / 64, (Hn / HPB) * g), 256, 0, stream>>>(qkvb, sb, b0);
        mid_kernel<<<g * Nn, 256, 0, stream>>>(sb, th1w, th1b, th2w, th2b);
        pv_kernel<<<dim3(Nn / 128, Hn * g), 256, 0, stream>>>(sb, vtb, xb, b0);
    }

    // final projection -> f32 out
    gemm128<false><<<dim3(Dn / 128, Rn / 128), 256, 0, stream>>>(
        xb, wob, bo, d_out, Rn, Dn, Dn);
}